// Round 1
// baseline (4425.570 us; speedup 1.0000x reference)
//
#include <hip/hip_runtime.h>
#include <math.h>

#define NQ   300
#define DMODEL 256
#define NHEAD 8
#define HDIM 32
#define BB   2
#define NKV  4096
#define DFF_ 1024
#define RPEH 512
#define NLAYER 6
#define ATTN_SCALE 0.17677669529663687f  // 1/sqrt(32)

// ---------------------------------------------------------------------------
// prep: kv = src + src_pos_embed ; box corners from reference_points
// ---------------------------------------------------------------------------
__global__ __launch_bounds__(256) void prep_kernel(
    const float* __restrict__ src, const float* __restrict__ spe,
    float* __restrict__ kv, const float* __restrict__ refp,
    float* __restrict__ boxx, float* __restrict__ boxy)
{
    int i = blockIdx.x * 256 + threadIdx.x;
    if (i < BB * NKV * DMODEL) kv[i] = src[i] + spe[i];
    if (i < BB * NQ) {
        float cx = refp[i * 4 + 0], cy = refp[i * 4 + 1];
        float w  = refp[i * 4 + 2], h  = refp[i * 4 + 3];
        boxx[i * 2 + 0] = cx - 0.5f * w;
        boxx[i * 2 + 1] = cx + 0.5f * w;
        boxy[i * 2 + 0] = cy - 0.5f * h;
        boxy[i * 2 + 1] = cy + 0.5f * h;
    }
}

// ---------------------------------------------------------------------------
// GEMM: C[M,N] = act( (A [+P]) @ W^T + bias [, *scale] )
// A: (M,K) row-major, W: (N,K) row-major. 64x64 tile, 256 thr, 4x4/thread.
// N must be a multiple of 64 (true here: 256/1024); M bounds-checked.
// ---------------------------------------------------------------------------
template<int ADDP, int RELU, int SCALED>
__global__ __launch_bounds__(256) void gemm_bias(
    const float* __restrict__ A, const float* __restrict__ P,
    const float* __restrict__ W, const float* __restrict__ bias,
    float* __restrict__ C, int M, int N, int K, float scale)
{
    __shared__ float As[16][68];
    __shared__ float Ws[16][68];
    const int t  = threadIdx.x;
    const int tx = t & 15, ty = t >> 4;
    const int m0 = blockIdx.y * 64, n0 = blockIdx.x * 64;
    float acc[4][4] = {};
    for (int k0 = 0; k0 < K; k0 += 16) {
#pragma unroll
        for (int i = 0; i < 4; ++i) {
            int e  = t + 256 * i;
            int mm = e >> 4, kk = e & 15;
            int m  = m0 + mm;
            float va = 0.f;
            if (m < M) {
                va = A[m * K + k0 + kk];
                if (ADDP) va += P[m * K + k0 + kk];
            }
            As[kk][mm] = va;
            Ws[kk][mm] = W[(n0 + mm) * K + k0 + kk];
        }
        __syncthreads();
#pragma unroll
        for (int kk = 0; kk < 16; ++kk) {
            float a[4], w[4];
#pragma unroll
            for (int i = 0; i < 4; ++i) a[i] = As[kk][ty + 16 * i];
#pragma unroll
            for (int j = 0; j < 4; ++j) w[j] = Ws[kk][tx + 16 * j];
#pragma unroll
            for (int i = 0; i < 4; ++i)
#pragma unroll
                for (int j = 0; j < 4; ++j) acc[i][j] += a[i] * w[j];
        }
        __syncthreads();
    }
#pragma unroll
    for (int i = 0; i < 4; ++i) {
        int m = m0 + ty + 16 * i;
        if (m >= M) continue;
#pragma unroll
        for (int j = 0; j < 4; ++j) {
            int n = n0 + tx + 16 * j;
            float v = acc[i][j] + bias[n];
            if (SCALED) v *= scale;
            if (RELU) v = fmaxf(v, 0.f);
            C[m * N + n] = v;
        }
    }
}

// ---------------------------------------------------------------------------
// LayerNorm(out + t) -> out, one wave per 256-wide row
// ---------------------------------------------------------------------------
__global__ __launch_bounds__(256) void ln_residual(
    float* __restrict__ out, const float* __restrict__ tt,
    const float* __restrict__ w, const float* __restrict__ b, int rows)
{
    const int wid = threadIdx.x >> 6, lane = threadIdx.x & 63;
    const int row = blockIdx.x * 4 + wid;
    if (row >= rows) return;
    const float* orow = out + row * DMODEL;
    const float* trow = tt + row * DMODEL;
    float x[4];
#pragma unroll
    for (int i = 0; i < 4; ++i) x[i] = orow[lane + 64 * i] + trow[lane + 64 * i];
    float s = x[0] + x[1] + x[2] + x[3];
#pragma unroll
    for (int mask = 1; mask < 64; mask <<= 1) s += __shfl_xor(s, mask);
    float mean = s * (1.f / 256.f);
    float vs = 0.f;
#pragma unroll
    for (int i = 0; i < 4; ++i) { float d = x[i] - mean; vs += d * d; }
#pragma unroll
    for (int mask = 1; mask < 64; mask <<= 1) vs += __shfl_xor(vs, mask);
    float r = rsqrtf(vs * (1.f / 256.f) + 1e-5f);
    float* orw = out + row * DMODEL;
#pragma unroll
    for (int i = 0; i < 4; ++i) {
        int c = lane + 64 * i;
        orw[c] = (x[i] - mean) * r * w[c] + b[c];
    }
}

// ---------------------------------------------------------------------------
// RPE MLP: per (b,q): for 64 positions on each axis,
// h = relu(d0*W1[:,0] + d1*W1[:,1] + b1) ; out[head] = h . W2[head,:]
// writes rx/ry as (B, NHEAD, NQ, 64)
// ---------------------------------------------------------------------------
__global__ __launch_bounds__(256) void rpe_kernel(
    const float* __restrict__ boxx, const float* __restrict__ boxy,
    const float* __restrict__ w1x, const float* __restrict__ b1x,
    const float* __restrict__ w2x,
    const float* __restrict__ w1y, const float* __restrict__ b1y,
    const float* __restrict__ w2y,
    float* __restrict__ rx, float* __restrict__ ry)
{
    const int bq = blockIdx.x;            // 0..599
    const int b = bq / NQ, q = bq % NQ;
    const int wid = threadIdx.x >> 6, lane = threadIdx.x & 63;

    for (int task = wid; task < 128; task += 4) {
        const int axis = task >> 6;
        const int i    = task & 63;
        const float* w1 = axis ? w1y : w1x;
        const float* b1 = axis ? b1y : b1x;
        const float* w2 = axis ? w2y : w2x;
        const float* bx = axis ? boxy : boxx;
        const float pos = (i + 0.5f) * 16.0f;
        const float d0 = bx[bq * 2 + 0] - pos;
        const float d1 = bx[bq * 2 + 1] - pos;
        float acc[8];
#pragma unroll
        for (int hh = 0; hh < 8; ++hh) acc[hh] = 0.f;
#pragma unroll
        for (int jj = 0; jj < 8; ++jj) {
            int j = lane + (jj << 6);
            float hv = fmaxf(d0 * w1[j * 2] + d1 * w1[j * 2 + 1] + b1[j], 0.f);
#pragma unroll
            for (int hh = 0; hh < 8; ++hh) acc[hh] += hv * w2[hh * RPEH + j];
        }
#pragma unroll
        for (int mask = 1; mask < 64; mask <<= 1)
#pragma unroll
            for (int hh = 0; hh < 8; ++hh) acc[hh] += __shfl_xor(acc[hh], mask);
        if (lane == 0) {
            float* dst = axis ? ry : rx;
#pragma unroll
            for (int hh = 0; hh < 8; ++hh)
                dst[((size_t)(b * NHEAD + hh) * NQ + q) * 64 + i] = acc[hh];
        }
    }
}

// ---------------------------------------------------------------------------
// Flash-style attention, one block per (b,h, 32-q-row tile). 8 lanes/row.
// HAS_RPE=1 adds rx/ry (B,NHEAD,NQ,64) bias: n -> (y=n>>6, x=n&63).
// Q/K/V/O layout: (B, rows, 256) with head offset h*32.
// ---------------------------------------------------------------------------
template<int HAS_RPE>
__global__ __launch_bounds__(256) void attn_kernel(
    const float* __restrict__ Q, const float* __restrict__ K,
    const float* __restrict__ V, float* __restrict__ O,
    const float* __restrict__ RX, const float* __restrict__ RY,
    int nq, int nkeys, float sscale)
{
    __shared__ float q_s[32][36];
    __shared__ float k_s[64][36];
    __shared__ float v_s[64][36];
    __shared__ float rx_s[HAS_RPE ? 32 : 1][64];
    __shared__ float ry_s[HAS_RPE ? 32 : 1][64];

    const int t = threadIdx.x;
    const int r = t >> 3, g = t & 7;
    const int bh = blockIdx.y;
    const int b = bh >> 3, h = bh & 7;
    const int q0 = blockIdx.x * 32;

    // stage Q tile (32 rows x 32 dims), float4
    {
        int e = t;  // 256 float4 = exactly one per thread
        int rr = e >> 3, d4 = e & 7;
        int qi = q0 + rr;
        float4 v4 = make_float4(0.f, 0.f, 0.f, 0.f);
        if (qi < nq) v4 = *(const float4*)&Q[((size_t)(b * nq + qi)) * DMODEL + h * HDIM + d4 * 4];
        *(float4*)&q_s[rr][d4 * 4] = v4;
    }
    if (HAS_RPE) {
        for (int e = t; e < 512; e += 256) {
            int rr = e >> 4, i4 = e & 15;
            int qi = q0 + rr;
            float4 vx = make_float4(0.f, 0.f, 0.f, 0.f), vy = vx;
            if (qi < nq) {
                vx = *(const float4*)&RX[(((size_t)(b * NHEAD + h) * nq) + qi) * 64 + i4 * 4];
                vy = *(const float4*)&RY[(((size_t)(b * NHEAD + h) * nq) + qi) * 64 + i4 * 4];
            }
            *(float4*)&rx_s[rr][i4 * 4] = vx;
            *(float4*)&ry_s[rr][i4 * 4] = vy;
        }
    }
    __syncthreads();

    float qr[32];
#pragma unroll
    for (int d = 0; d < 32; ++d) qr[d] = q_s[r][d];

    float m = -1e30f, l = 0.f;
    float o[32];
#pragma unroll
    for (int d = 0; d < 32; ++d) o[d] = 0.f;

    const int ntiles = (nkeys + 63) >> 6;
    for (int kt = 0; kt < ntiles; ++kt) {
        const int nbase = kt << 6;
        __syncthreads();
        for (int e = t; e < 512; e += 256) {
            int nn = e >> 3, d4 = e & 7;
            int nk = nbase + nn;
            float4 kk4 = make_float4(0.f, 0.f, 0.f, 0.f), vv4 = kk4;
            if (nk < nkeys) {
                kk4 = *(const float4*)&K[((size_t)(b * nkeys + nk)) * DMODEL + h * HDIM + d4 * 4];
                vv4 = *(const float4*)&V[((size_t)(b * nkeys + nk)) * DMODEL + h * HDIM + d4 * 4];
            }
            *(float4*)&k_s[nn][d4 * 4] = kk4;
            *(float4*)&v_s[nn][d4 * 4] = vv4;
        }
        __syncthreads();

        float s[8];
        float tmax = -1e30f;
#pragma unroll
        for (int jj = 0; jj < 8; ++jj) {
            int nl = g + (jj << 3);
            int nk = nbase + nl;
            float sv = -1e30f;
            if (nk < nkeys) {
                float acc = 0.f;
#pragma unroll
                for (int d = 0; d < 32; ++d) acc += qr[d] * k_s[nl][d];
                sv = acc * sscale;
                if (HAS_RPE) sv += ry_s[r][nk >> 6] + rx_s[r][nk & 63];
            }
            s[jj] = sv;
            tmax = fmaxf(tmax, sv);
        }
        float mn = fmaxf(m, tmax);
        float c = __expf(m - mn);
        l *= c;
#pragma unroll
        for (int d = 0; d < 32; ++d) o[d] *= c;
        m = mn;
#pragma unroll
        for (int jj = 0; jj < 8; ++jj) {
            int nl = g + (jj << 3);
            float p = __expf(s[jj] - m);
            l += p;
#pragma unroll
            for (int d = 0; d < 32; ++d) o[d] += p * v_s[nl][d];
        }
    }

    // combine the 8 lanes of this row group (butterfly keeps all lanes equal)
#pragma unroll
    for (int mask = 1; mask < 8; mask <<= 1) {
        float m2 = __shfl_xor(m, mask);
        float l2 = __shfl_xor(l, mask);
        float mn = fmaxf(m, m2);
        float c1 = __expf(m - mn), c2 = __expf(m2 - mn);
        l = l * c1 + l2 * c2;
#pragma unroll
        for (int d = 0; d < 32; ++d) o[d] = o[d] * c1 + __shfl_xor(o[d], mask) * c2;
        m = mn;
    }
    const int qi = q0 + r;
    if (g == 0 && qi < nq) {
        float inv = 1.f / l;
#pragma unroll
        for (int d = 0; d < 32; ++d)
            O[((size_t)(b * nq + qi)) * DMODEL + h * HDIM + d] = o[d] * inv;
    }
}

// ---------------------------------------------------------------------------
extern "C" void kernel_launch(void* const* d_in, const int* in_sizes, int n_in,
                              void* d_out, int out_size, void* d_ws, size_t ws_size,
                              hipStream_t stream)
{
    const float* tgt   = (const float*)d_in[0];
    const float* qpos  = (const float*)d_in[1];
    const float* refp  = (const float*)d_in[2];
    const float* src   = (const float*)d_in[3];
    const float* spe   = (const float*)d_in[4];
    const float* sa_in_w  = (const float*)d_in[6];
    const float* sa_in_b  = (const float*)d_in[7];
    const float* sa_out_w = (const float*)d_in[8];
    const float* sa_out_b = (const float*)d_in[9];
    const float* n1_w  = (const float*)d_in[10];
    const float* n1_b  = (const float*)d_in[11];
    const float* ca_q_w = (const float*)d_in[12];
    const float* ca_q_b = (const float*)d_in[13];
    const float* ca_k_w = (const float*)d_in[14];
    const float* ca_k_b = (const float*)d_in[15];
    const float* ca_v_w = (const float*)d_in[16];
    const float* ca_v_b = (const float*)d_in[17];
    const float* ca_p_w = (const float*)d_in[18];
    const float* ca_p_b = (const float*)d_in[19];
    const float* cpb1_w1 = (const float*)d_in[20];
    const float* cpb1_b1 = (const float*)d_in[21];
    const float* cpb1_w2 = (const float*)d_in[22];
    const float* cpb2_w1 = (const float*)d_in[23];
    const float* cpb2_b1 = (const float*)d_in[24];
    const float* cpb2_w2 = (const float*)d_in[25];
    const float* n2_w = (const float*)d_in[26];
    const float* n2_b = (const float*)d_in[27];
    const float* ffn_w1 = (const float*)d_in[28];
    const float* ffn_b1 = (const float*)d_in[29];
    const float* ffn_w2 = (const float*)d_in[30];
    const float* ffn_b2 = (const float*)d_in[31];
    const float* n3_w = (const float*)d_in[32];
    const float* n3_b = (const float*)d_in[33];

    float* ws  = (float*)d_ws;
    float* kv   = ws;                 // 2*4096*256
    float* Kc   = kv + 2097152;       // 2*4096*256
    float* Vc   = Kc + 2097152;       // 2*4096*256
    float* outb = Vc + 2097152;       // 600*256
    float* qb   = outb + 153600;
    float* kb   = qb + 153600;
    float* vb   = kb + 153600;
    float* ob   = vb + 153600;
    float* tb   = ob + 153600;
    float* hb   = tb + 153600;        // 600*1024
    float* rx   = hb + 614400;        // 2*8*300*64
    float* ry   = rx + 307200;
    float* boxx = ry + 307200;        // 600*2
    float* boxy = boxx + 1200;

    const int M = BB * NQ;            // 600
    const int MK = BB * NKV;          // 8192

    prep_kernel<<<8192, 256, 0, stream>>>(src, spe, kv, refp, boxx, boxy);
    hipMemcpyAsync(outb, tgt, (size_t)M * DMODEL * sizeof(float),
                   hipMemcpyDeviceToDevice, stream);

    for (int l = 0; l < NLAYER; ++l) {
        const float* saw = sa_in_w + (size_t)l * 768 * 256;
        const float* sab = sa_in_b + (size_t)l * 768;

        // ---- self attention ----
        gemm_bias<1,0,0><<<dim3(4,10),256,0,stream>>>(outb, qpos, saw,           sab,       qb, M, 256, 256, 1.f);
        gemm_bias<1,0,0><<<dim3(4,10),256,0,stream>>>(outb, qpos, saw + 65536,   sab + 256, kb, M, 256, 256, 1.f);
        gemm_bias<0,0,0><<<dim3(4,10),256,0,stream>>>(outb, nullptr, saw + 131072, sab + 512, vb, M, 256, 256, 1.f);
        attn_kernel<0><<<dim3(10,16),256,0,stream>>>(qb, kb, vb, ob, nullptr, nullptr, NQ, NQ, ATTN_SCALE);
        gemm_bias<0,0,0><<<dim3(4,10),256,0,stream>>>(ob, nullptr, sa_out_w + (size_t)l*65536, sa_out_b + l*256, tb, M, 256, 256, 1.f);
        ln_residual<<<150,256,0,stream>>>(outb, tb, n1_w + l*256, n1_b + l*256, M);

        // ---- cross attention ----
        gemm_bias<1,0,1><<<dim3(4,10),256,0,stream>>>(outb, qpos, ca_q_w + (size_t)l*65536, ca_q_b + l*256, qb, M, 256, 256, ATTN_SCALE);
        gemm_bias<0,0,0><<<dim3(4,128),256,0,stream>>>(kv,  nullptr, ca_k_w + (size_t)l*65536, ca_k_b + l*256, Kc, MK, 256, 256, 1.f);
        gemm_bias<0,0,0><<<dim3(4,128),256,0,stream>>>(src, nullptr, ca_v_w + (size_t)l*65536, ca_v_b + l*256, Vc, MK, 256, 256, 1.f);
        rpe_kernel<<<600,256,0,stream>>>(boxx, boxy,
            cpb1_w1 + (size_t)l*1024, cpb1_b1 + (size_t)l*512, cpb1_w2 + (size_t)l*4096,
            cpb2_w1 + (size_t)l*1024, cpb2_b1 + (size_t)l*512, cpb2_w2 + (size_t)l*4096,
            rx, ry);
        attn_kernel<1><<<dim3(10,16),256,0,stream>>>(qb, Kc, Vc, ob, rx, ry, NQ, NKV, 1.0f);
        gemm_bias<0,0,0><<<dim3(4,10),256,0,stream>>>(ob, nullptr, ca_p_w + (size_t)l*65536, ca_p_b + l*256, tb, M, 256, 256, 1.f);
        ln_residual<<<150,256,0,stream>>>(outb, tb, n2_w + l*256, n2_b + l*256, M);

        // ---- FFN ----
        gemm_bias<0,1,0><<<dim3(16,10),256,0,stream>>>(outb, nullptr, ffn_w1 + (size_t)l*262144, ffn_b1 + l*1024, hb, M, 1024, 256, 1.f);
        gemm_bias<0,0,0><<<dim3(4,10),256,0,stream>>>(hb, nullptr, ffn_w2 + (size_t)l*262144, ffn_b2 + l*256, tb, M, 256, 1024, 1.f);
        ln_residual<<<150,256,0,stream>>>(outb, tb, n3_w + l*256, n3_b + l*256, M);
    }

    hipMemcpyAsync(d_out, outb, (size_t)M * DMODEL * sizeof(float),
                   hipMemcpyDeviceToDevice, stream);
}

// Round 2
// 2278.171 us; speedup vs baseline: 1.9426x; 1.9426x over previous
//
#include <hip/hip_runtime.h>
#include <math.h>

#define NQ   300
#define DMODEL 256
#define NHEAD 8
#define HDIM 32
#define BB   2
#define NKV  4096
#define DFF_ 1024
#define RPEH 512
#define NLAYER 6
#define NSPLIT 4
#define ATTN_SCALE 0.17677669529663687f  // 1/sqrt(32)

// ---------------------------------------------------------------------------
// prep: kv = src + src_pos_embed ; box corners from reference_points
// ---------------------------------------------------------------------------
__global__ __launch_bounds__(256) void prep_kernel(
    const float* __restrict__ src, const float* __restrict__ spe,
    float* __restrict__ kv, const float* __restrict__ refp,
    float* __restrict__ boxx, float* __restrict__ boxy)
{
    int i = blockIdx.x * 256 + threadIdx.x;
    if (i < BB * NKV * DMODEL) kv[i] = src[i] + spe[i];
    if (i < BB * NQ) {
        float cx = refp[i * 4 + 0], cy = refp[i * 4 + 1];
        float w  = refp[i * 4 + 2], h  = refp[i * 4 + 3];
        boxx[i * 2 + 0] = cx - 0.5f * w;
        boxx[i * 2 + 1] = cx + 0.5f * w;
        boxy[i * 2 + 0] = cy - 0.5f * h;
        boxy[i * 2 + 1] = cy + 0.5f * h;
    }
}

// ---------------------------------------------------------------------------
// GEMM core: C[M,N] = act(((A [+P if n0<plimit]) @ W^T + bias) * scale)
// A: (M,K) row-major, W: (N,K) row-major. 64x64 tile, 256 thr, 4x4/thread.
// All-float4 staging / LDS reads / C stores. N multiple of 64; M bounds-checked.
// ---------------------------------------------------------------------------
__device__ __forceinline__ void gemm_core(
    const float* __restrict__ A, const float* __restrict__ P, int plimit,
    const float* __restrict__ W, const float* __restrict__ bias,
    float* __restrict__ C, int M, int N, int K, float scale, int relu,
    int m0, int n0)
{
    __shared__ float As[16][68];
    __shared__ float Ws[16][68];
    const int t  = threadIdx.x;
    const int tx = t & 15, ty = t >> 4;
    const bool addp = (P != nullptr) && (n0 < plimit);
    const int mm = t >> 2, kc = t & 3;   // staging coords: 64 rows x 4 float4
    float acc[4][4] = {};
    for (int k0 = 0; k0 < K; k0 += 16) {
        {
            int m = m0 + mm;
            float4 va = make_float4(0.f, 0.f, 0.f, 0.f);
            if (m < M) {
                va = *(const float4*)&A[(size_t)m * K + k0 + 4 * kc];
                if (addp) {
                    float4 p4 = *(const float4*)&P[(size_t)m * K + k0 + 4 * kc];
                    va.x += p4.x; va.y += p4.y; va.z += p4.z; va.w += p4.w;
                }
            }
            As[4 * kc + 0][mm] = va.x;
            As[4 * kc + 1][mm] = va.y;
            As[4 * kc + 2][mm] = va.z;
            As[4 * kc + 3][mm] = va.w;
            float4 vw = *(const float4*)&W[(size_t)(n0 + mm) * K + k0 + 4 * kc];
            Ws[4 * kc + 0][mm] = vw.x;
            Ws[4 * kc + 1][mm] = vw.y;
            Ws[4 * kc + 2][mm] = vw.z;
            Ws[4 * kc + 3][mm] = vw.w;
        }
        __syncthreads();
#pragma unroll
        for (int kk = 0; kk < 16; ++kk) {
            float4 a4 = *(const float4*)&As[kk][4 * ty];
            float4 w4 = *(const float4*)&Ws[kk][4 * tx];
            float a[4] = {a4.x, a4.y, a4.z, a4.w};
            float w[4] = {w4.x, w4.y, w4.z, w4.w};
#pragma unroll
            for (int i = 0; i < 4; ++i)
#pragma unroll
                for (int j = 0; j < 4; ++j) acc[i][j] += a[i] * w[j];
        }
        __syncthreads();
    }
#pragma unroll
    for (int i = 0; i < 4; ++i) {
        int m = m0 + 4 * ty + i;
        if (m >= M) continue;
        float4 o4;
        float v0 = (acc[i][0] + bias[n0 + 4 * tx + 0]) * scale;
        float v1 = (acc[i][1] + bias[n0 + 4 * tx + 1]) * scale;
        float v2 = (acc[i][2] + bias[n0 + 4 * tx + 2]) * scale;
        float v3 = (acc[i][3] + bias[n0 + 4 * tx + 3]) * scale;
        if (relu) {
            v0 = fmaxf(v0, 0.f); v1 = fmaxf(v1, 0.f);
            v2 = fmaxf(v2, 0.f); v3 = fmaxf(v3, 0.f);
        }
        o4.x = v0; o4.y = v1; o4.z = v2; o4.w = v3;
        *(float4*)&C[(size_t)m * N + n0 + 4 * tx] = o4;
    }
}

__global__ __launch_bounds__(256) void gemm_bias(
    const float* __restrict__ A, const float* __restrict__ P, int plimit,
    const float* __restrict__ W, const float* __restrict__ bias,
    float* __restrict__ C, int M, int N, int K, float scale, int relu)
{
    gemm_core(A, P, plimit, W, bias, C, M, N, K, scale, relu,
              blockIdx.y * 64, blockIdx.x * 64);
}

// two independent GEMMs (same M,N,K) selected by blockIdx.z
__global__ __launch_bounds__(256) void gemm_dual(
    const float* __restrict__ A0, const float* __restrict__ A1,
    const float* __restrict__ W0, const float* __restrict__ W1,
    const float* __restrict__ b0, const float* __restrict__ b1,
    float* __restrict__ C0, float* __restrict__ C1, int M, int N, int K)
{
    if (blockIdx.z == 0)
        gemm_core(A0, nullptr, 0, W0, b0, C0, M, N, K, 1.f, 0,
                  blockIdx.y * 64, blockIdx.x * 64);
    else
        gemm_core(A1, nullptr, 0, W1, b1, C1, M, N, K, 1.f, 0,
                  blockIdx.y * 64, blockIdx.x * 64);
}

// ---------------------------------------------------------------------------
// LayerNorm(out + t) -> out, one wave per 256-wide row
// ---------------------------------------------------------------------------
__global__ __launch_bounds__(256) void ln_residual(
    float* __restrict__ out, const float* __restrict__ tt,
    const float* __restrict__ w, const float* __restrict__ b, int rows)
{
    const int wid = threadIdx.x >> 6, lane = threadIdx.x & 63;
    const int row = blockIdx.x * 4 + wid;
    if (row >= rows) return;
    const float* orow = out + row * DMODEL;
    const float* trow = tt + row * DMODEL;
    float x[4];
#pragma unroll
    for (int i = 0; i < 4; ++i) x[i] = orow[lane + 64 * i] + trow[lane + 64 * i];
    float s = x[0] + x[1] + x[2] + x[3];
#pragma unroll
    for (int mask = 1; mask < 64; mask <<= 1) s += __shfl_xor(s, mask);
    float mean = s * (1.f / 256.f);
    float vs = 0.f;
#pragma unroll
    for (int i = 0; i < 4; ++i) { float d = x[i] - mean; vs += d * d; }
#pragma unroll
    for (int mask = 1; mask < 64; mask <<= 1) vs += __shfl_xor(vs, mask);
    float r = rsqrtf(vs * (1.f / 256.f) + 1e-5f);
    float* orw = out + row * DMODEL;
#pragma unroll
    for (int i = 0; i < 4; ++i) {
        int c = lane + 64 * i;
        orw[c] = (x[i] - mean) * r * w[c] + b[c];
    }
}

// ---------------------------------------------------------------------------
// RPE MLP (writes rx/ry as (B, NHEAD, NQ, 64))
// ---------------------------------------------------------------------------
__global__ __launch_bounds__(256) void rpe_kernel(
    const float* __restrict__ boxx, const float* __restrict__ boxy,
    const float* __restrict__ w1x, const float* __restrict__ b1x,
    const float* __restrict__ w2x,
    const float* __restrict__ w1y, const float* __restrict__ b1y,
    const float* __restrict__ w2y,
    float* __restrict__ rx, float* __restrict__ ry)
{
    const int bq = blockIdx.x;            // 0..599
    const int b = bq / NQ, q = bq % NQ;
    const int wid = threadIdx.x >> 6, lane = threadIdx.x & 63;

    for (int task = wid; task < 128; task += 4) {
        const int axis = task >> 6;
        const int i    = task & 63;
        const float* w1 = axis ? w1y : w1x;
        const float* b1 = axis ? b1y : b1x;
        const float* w2 = axis ? w2y : w2x;
        const float* bx = axis ? boxy : boxx;
        const float pos = (i + 0.5f) * 16.0f;
        const float d0 = bx[bq * 2 + 0] - pos;
        const float d1 = bx[bq * 2 + 1] - pos;
        float acc[8];
#pragma unroll
        for (int hh = 0; hh < 8; ++hh) acc[hh] = 0.f;
#pragma unroll
        for (int jj = 0; jj < 8; ++jj) {
            int j = lane + (jj << 6);
            float hv = fmaxf(d0 * w1[j * 2] + d1 * w1[j * 2 + 1] + b1[j], 0.f);
#pragma unroll
            for (int hh = 0; hh < 8; ++hh) acc[hh] += hv * w2[hh * RPEH + j];
        }
#pragma unroll
        for (int mask = 1; mask < 64; mask <<= 1)
#pragma unroll
            for (int hh = 0; hh < 8; ++hh) acc[hh] += __shfl_xor(acc[hh], mask);
        if (lane == 0) {
            float* dst = axis ? ry : rx;
#pragma unroll
            for (int hh = 0; hh < 8; ++hh)
                dst[((size_t)(b * NHEAD + hh) * NQ + q) * 64 + i] = acc[hh];
        }
    }
}

// ---------------------------------------------------------------------------
// Self-attention (full keys, writes normalized O). 8 lanes per q-row.
// ---------------------------------------------------------------------------
__global__ __launch_bounds__(256) void attn_self(
    const float* __restrict__ Q, const float* __restrict__ K,
    const float* __restrict__ V, float* __restrict__ O,
    int nq, int nkeys, float sscale, int ldq, int ldk)
{
    __shared__ float q_s[32][40];
    __shared__ float k_s[64][40];
    __shared__ float v_s[64][40];

    const int t = threadIdx.x;
    const int r = t >> 3, g = t & 7;
    const int bh = blockIdx.y;
    const int b = bh >> 3, h = bh & 7;
    const int q0 = blockIdx.x * 32;

    {
        int rr = t >> 3, d4 = t & 7;
        int qi = q0 + rr;
        float4 v4 = make_float4(0.f, 0.f, 0.f, 0.f);
        if (qi < nq) v4 = *(const float4*)&Q[((size_t)(b * nq + qi)) * ldq + h * HDIM + d4 * 4];
        *(float4*)&q_s[rr][d4 * 4] = v4;
    }
    __syncthreads();

    float qr[32];
#pragma unroll
    for (int d = 0; d < 32; ++d) qr[d] = q_s[r][d];

    float m = -1e30f, l = 0.f;
    float o[32];
#pragma unroll
    for (int d = 0; d < 32; ++d) o[d] = 0.f;

    const int ntiles = (nkeys + 63) >> 6;
    for (int kt = 0; kt < ntiles; ++kt) {
        const int nbase = kt << 6;
        __syncthreads();
        for (int e = t; e < 512; e += 256) {
            int nn = e >> 3, d4 = e & 7;
            int nk = nbase + nn;
            float4 kk4 = make_float4(0.f, 0.f, 0.f, 0.f), vv4 = kk4;
            if (nk < nkeys) {
                kk4 = *(const float4*)&K[((size_t)(b * nkeys + nk)) * ldk + h * HDIM + d4 * 4];
                vv4 = *(const float4*)&V[((size_t)(b * nkeys + nk)) * ldk + h * HDIM + d4 * 4];
            }
            *(float4*)&k_s[nn][d4 * 4] = kk4;
            *(float4*)&v_s[nn][d4 * 4] = vv4;
        }
        __syncthreads();

        float s[8];
        float tmax = -1e30f;
#pragma unroll
        for (int jj = 0; jj < 8; ++jj) {
            int nl = g + (jj << 3);
            int nk = nbase + nl;
            float sv = -1e30f;
            if (nk < nkeys) {
                float acc = 0.f;
#pragma unroll
                for (int d = 0; d < 32; ++d) acc += qr[d] * k_s[nl][d];
                sv = acc * sscale;
            }
            s[jj] = sv;
            tmax = fmaxf(tmax, sv);
        }
        float mn = fmaxf(m, tmax);
        float c = __expf(m - mn);
        l *= c;
#pragma unroll
        for (int d = 0; d < 32; ++d) o[d] *= c;
        m = mn;
#pragma unroll
        for (int jj = 0; jj < 8; ++jj) {
            int nl = g + (jj << 3);
            float p = __expf(s[jj] - m);
            l += p;
#pragma unroll
            for (int d = 0; d < 32; ++d) o[d] += p * v_s[nl][d];
        }
    }

#pragma unroll
    for (int mask = 1; mask < 8; mask <<= 1) {
        float m2 = __shfl_xor(m, mask);
        float l2 = __shfl_xor(l, mask);
        float mn = fmaxf(m, m2);
        float c1 = __expf(m - mn), c2 = __expf(m2 - mn);
        l = l * c1 + l2 * c2;
#pragma unroll
        for (int d = 0; d < 32; ++d) o[d] = o[d] * c1 + __shfl_xor(o[d], mask) * c2;
        m = mn;
    }
    const int qi = q0 + r;
    if (g == 0 && qi < nq) {
        float inv = 1.f / l;
#pragma unroll
        for (int d = 0; d < 32; ++d)
            O[((size_t)(b * nq + qi)) * DMODEL + h * HDIM + d] = o[d] * inv;
    }
}

// ---------------------------------------------------------------------------
// Cross-attention, split over KV: blockIdx.z = split (NSPLIT x 1024 keys).
// Writes unnormalized partial o + (m, l) per (bh, split, q).
// ---------------------------------------------------------------------------
__global__ __launch_bounds__(256) void attn_cross_split(
    const float* __restrict__ Q, const float* __restrict__ K,
    const float* __restrict__ V,
    const float* __restrict__ RX, const float* __restrict__ RY,
    float* __restrict__ po, float* __restrict__ pm, float* __restrict__ pl)
{
    __shared__ float q_s[32][40];
    __shared__ float k_s[64][40];
    __shared__ float v_s[64][40];
    __shared__ float rx_s[32][64];
    __shared__ float ry_s[32][64];

    const int t = threadIdx.x;
    const int r = t >> 3, g = t & 7;
    const int bh = blockIdx.y;
    const int b = bh >> 3, h = bh & 7;
    const int q0 = blockIdx.x * 32;
    const int sp = blockIdx.z;
    const int kbase0 = sp * (NKV / NSPLIT);

    {
        int rr = t >> 3, d4 = t & 7;
        int qi = q0 + rr;
        float4 v4 = make_float4(0.f, 0.f, 0.f, 0.f);
        if (qi < NQ) v4 = *(const float4*)&Q[((size_t)(b * NQ + qi)) * DMODEL + h * HDIM + d4 * 4];
        *(float4*)&q_s[rr][d4 * 4] = v4;
    }
    for (int e = t; e < 512; e += 256) {
        int rr = e >> 4, i4 = e & 15;
        int qi = q0 + rr;
        float4 vx = make_float4(0.f, 0.f, 0.f, 0.f), vy = vx;
        if (qi < NQ) {
            vx = *(const float4*)&RX[(((size_t)(b * NHEAD + h) * NQ) + qi) * 64 + i4 * 4];
            vy = *(const float4*)&RY[(((size_t)(b * NHEAD + h) * NQ) + qi) * 64 + i4 * 4];
        }
        *(float4*)&rx_s[rr][i4 * 4] = vx;
        *(float4*)&ry_s[rr][i4 * 4] = vy;
    }
    __syncthreads();

    float qr[32];
#pragma unroll
    for (int d = 0; d < 32; ++d) qr[d] = q_s[r][d];

    float m = -1e30f, l = 0.f;
    float o[32];
#pragma unroll
    for (int d = 0; d < 32; ++d) o[d] = 0.f;

    const int ntiles = (NKV / NSPLIT) >> 6;   // 16
    for (int kt = 0; kt < ntiles; ++kt) {
        const int nbase = kbase0 + (kt << 6);
        __syncthreads();
        for (int e = t; e < 512; e += 256) {
            int nn = e >> 3, d4 = e & 7;
            int nk = nbase + nn;
            float4 kk4 = *(const float4*)&K[((size_t)(b * NKV + nk)) * DMODEL + h * HDIM + d4 * 4];
            float4 vv4 = *(const float4*)&V[((size_t)(b * NKV + nk)) * DMODEL + h * HDIM + d4 * 4];
            *(float4*)&k_s[nn][d4 * 4] = kk4;
            *(float4*)&v_s[nn][d4 * 4] = vv4;
        }
        __syncthreads();

        float s[8];
        float tmax = -1e30f;
#pragma unroll
        for (int jj = 0; jj < 8; ++jj) {
            int nl = g + (jj << 3);
            int nk = nbase + nl;
            float acc = 0.f;
#pragma unroll
            for (int d = 0; d < 32; ++d) acc += qr[d] * k_s[nl][d];
            float sv = acc + ry_s[r][nk >> 6] + rx_s[r][nk & 63];
            s[jj] = sv;
            tmax = fmaxf(tmax, sv);
        }
        float mn = fmaxf(m, tmax);
        float c = __expf(m - mn);
        l *= c;
#pragma unroll
        for (int d = 0; d < 32; ++d) o[d] *= c;
        m = mn;
#pragma unroll
        for (int jj = 0; jj < 8; ++jj) {
            int nl = g + (jj << 3);
            float p = __expf(s[jj] - m);
            l += p;
#pragma unroll
            for (int d = 0; d < 32; ++d) o[d] += p * v_s[nl][d];
        }
    }

#pragma unroll
    for (int mask = 1; mask < 8; mask <<= 1) {
        float m2 = __shfl_xor(m, mask);
        float l2 = __shfl_xor(l, mask);
        float mn = fmaxf(m, m2);
        float c1 = __expf(m - mn), c2 = __expf(m2 - mn);
        l = l * c1 + l2 * c2;
#pragma unroll
        for (int d = 0; d < 32; ++d) o[d] = o[d] * c1 + __shfl_xor(o[d], mask) * c2;
        m = mn;
    }
    const int qi = q0 + r;
    if (g == 0 && qi < NQ) {
        size_t base = ((size_t)(bh * NSPLIT + sp) * NQ + qi);
        pm[base] = m;
        pl[base] = l;
#pragma unroll
        for (int d = 0; d < 32; ++d) po[base * 32 + d] = o[d];
    }
}

// combine NSPLIT partials -> O. 32-lane group per (bh, q).
__global__ __launch_bounds__(256) void attn_combine(
    const float* __restrict__ po, const float* __restrict__ pm,
    const float* __restrict__ pl, float* __restrict__ O)
{
    int gid = blockIdx.x * 8 + (threadIdx.x >> 5);
    int lane = threadIdx.x & 31;
    if (gid >= 16 * NQ) return;
    int bh = gid / NQ, q = gid % NQ;
    int b = bh >> 3, h = bh & 7;
    float M = -1e30f;
#pragma unroll
    for (int s = 0; s < NSPLIT; ++s)
        M = fmaxf(M, pm[(size_t)(bh * NSPLIT + s) * NQ + q]);
    float L = 0.f, acc = 0.f;
#pragma unroll
    for (int s = 0; s < NSPLIT; ++s) {
        size_t base = (size_t)(bh * NSPLIT + s) * NQ + q;
        float w = __expf(pm[base] - M);
        L += pl[base] * w;
        acc += po[base * 32 + lane] * w;
    }
    O[((size_t)(b * NQ + q)) * DMODEL + h * HDIM + lane] = acc / L;
}

// ---------------------------------------------------------------------------
extern "C" void kernel_launch(void* const* d_in, const int* in_sizes, int n_in,
                              void* d_out, int out_size, void* d_ws, size_t ws_size,
                              hipStream_t stream)
{
    const float* tgt   = (const float*)d_in[0];
    const float* qpos  = (const float*)d_in[1];
    const float* refp  = (const float*)d_in[2];
    const float* src   = (const float*)d_in[3];
    const float* spe   = (const float*)d_in[4];
    const float* sa_in_w  = (const float*)d_in[6];
    const float* sa_in_b  = (const float*)d_in[7];
    const float* sa_out_w = (const float*)d_in[8];
    const float* sa_out_b = (const float*)d_in[9];
    const float* n1_w  = (const float*)d_in[10];
    const float* n1_b  = (const float*)d_in[11];
    const float* ca_q_w = (const float*)d_in[12];
    const float* ca_q_b = (const float*)d_in[13];
    const float* ca_k_w = (const float*)d_in[14];
    const float* ca_k_b = (const float*)d_in[15];
    const float* ca_v_w = (const float*)d_in[16];
    const float* ca_v_b = (const float*)d_in[17];
    const float* ca_p_w = (const float*)d_in[18];
    const float* ca_p_b = (const float*)d_in[19];
    const float* cpb1_w1 = (const float*)d_in[20];
    const float* cpb1_b1 = (const float*)d_in[21];
    const float* cpb1_w2 = (const float*)d_in[22];
    const float* cpb2_w1 = (const float*)d_in[23];
    const float* cpb2_b1 = (const float*)d_in[24];
    const float* cpb2_w2 = (const float*)d_in[25];
    const float* n2_w = (const float*)d_in[26];
    const float* n2_b = (const float*)d_in[27];
    const float* ffn_w1 = (const float*)d_in[28];
    const float* ffn_b1 = (const float*)d_in[29];
    const float* ffn_w2 = (const float*)d_in[30];
    const float* ffn_b2 = (const float*)d_in[31];
    const float* n3_w = (const float*)d_in[32];
    const float* n3_b = (const float*)d_in[33];

    float* ws  = (float*)d_ws;
    float* kv   = ws;                 // 2*4096*256
    float* Kc   = kv + 2097152;       // 2*4096*256
    float* Vc   = Kc + 2097152;       // 2*4096*256
    float* outb = Vc + 2097152;       // 600*256
    float* qb   = outb + 153600;      // fused qkv base (600*768 spans qb..vb)
    float* kb   = qb + 153600;
    float* vb   = kb + 153600;
    float* ob   = vb + 153600;
    float* tb   = ob + 153600;
    float* hb   = tb + 153600;        // 600*1024
    float* rx   = hb + 614400;        // 2*8*300*64
    float* ry   = rx + 307200;
    float* boxx = ry + 307200;        // 600*2
    float* boxy = boxx + 1200;
    // attention partials alias FFN scratch (free during attention):
    float* po = hb;                   // 16*NSPLIT*300*32 = 614400 floats
    float* pm = tb;                   // 16*NSPLIT*300 = 19200
    float* pl = tb + 19200;           // 19200
    (void)kb; (void)vb;

    const int M = BB * NQ;            // 600
    const int MK = BB * NKV;          // 8192

    prep_kernel<<<8192, 256, 0, stream>>>(src, spe, kv, refp, boxx, boxy);
    hipMemcpyAsync(outb, tgt, (size_t)M * DMODEL * sizeof(float),
                   hipMemcpyDeviceToDevice, stream);

    for (int l = 0; l < NLAYER; ++l) {
        const float* saw = sa_in_w + (size_t)l * 768 * 256;
        const float* sab = sa_in_b + (size_t)l * 768;

        // ---- self attention ----
        // fused QKV: N=768, +query_pos only for q/k output ranges (n < 512)
        gemm_bias<<<dim3(12, 10), 256, 0, stream>>>(outb, qpos, 512, saw, sab,
                                                    qb, M, 768, 256, 1.f, 0);
        attn_self<<<dim3(10, 16), 256, 0, stream>>>(qb, qb + 256, qb + 512, ob,
                                                    NQ, NQ, ATTN_SCALE, 768, 768);
        gemm_bias<<<dim3(4, 10), 256, 0, stream>>>(ob, nullptr, 0,
            sa_out_w + (size_t)l * 65536, sa_out_b + l * 256, tb, M, 256, 256, 1.f, 0);
        ln_residual<<<150, 256, 0, stream>>>(outb, tb, n1_w + l * 256, n1_b + l * 256, M);

        // ---- cross attention ----
        gemm_bias<<<dim3(4, 10), 256, 0, stream>>>(outb, qpos, 256,
            ca_q_w + (size_t)l * 65536, ca_q_b + l * 256, qb, M, 256, 256, ATTN_SCALE, 0);
        gemm_dual<<<dim3(4, 128, 2), 256, 0, stream>>>(kv, src,
            ca_k_w + (size_t)l * 65536, ca_v_w + (size_t)l * 65536,
            ca_k_b + l * 256, ca_v_b + l * 256, Kc, Vc, MK, 256, 256);
        rpe_kernel<<<600, 256, 0, stream>>>(boxx, boxy,
            cpb1_w1 + (size_t)l * 1024, cpb1_b1 + (size_t)l * 512, cpb1_w2 + (size_t)l * 4096,
            cpb2_w1 + (size_t)l * 1024, cpb2_b1 + (size_t)l * 512, cpb2_w2 + (size_t)l * 4096,
            rx, ry);
        attn_cross_split<<<dim3(10, 16, NSPLIT), 256, 0, stream>>>(qb, Kc, Vc, rx, ry,
                                                                   po, pm, pl);
        attn_combine<<<600, 256, 0, stream>>>(po, pm, pl, ob);
        gemm_bias<<<dim3(4, 10), 256, 0, stream>>>(ob, nullptr, 0,
            ca_p_w + (size_t)l * 65536, ca_p_b + l * 256, tb, M, 256, 256, 1.f, 0);
        ln_residual<<<150, 256, 0, stream>>>(outb, tb, n2_w + l * 256, n2_b + l * 256, M);

        // ---- FFN ----
        gemm_bias<<<dim3(16, 10), 256, 0, stream>>>(outb, nullptr, 0,
            ffn_w1 + (size_t)l * 262144, ffn_b1 + l * 1024, hb, M, 1024, 256, 1.f, 1);
        gemm_bias<<<dim3(4, 10), 256, 0, stream>>>(hb, nullptr, 0,
            ffn_w2 + (size_t)l * 262144, ffn_b2 + l * 256, tb, M, 256, 1024, 1.f, 0);
        ln_residual<<<150, 256, 0, stream>>>(outb, tb, n3_w + l * 256, n3_b + l * 256, M);
    }

    hipMemcpyAsync(d_out, outb, (size_t)M * DMODEL * sizeof(float),
                   hipMemcpyDeviceToDevice, stream);
}

// Round 3
// 1869.633 us; speedup vs baseline: 2.3671x; 1.2185x over previous
//
#include <hip/hip_runtime.h>
#include <math.h>

#define NQ   300
#define DMODEL 256
#define NHEAD 8
#define HDIM 32
#define BB   2
#define NKV  4096
#define DFF_ 1024
#define RPEH 512
#define NLAYER 6
#define NSPLIT 4
#define ATTN_SCALE 0.17677669529663687f  // 1/sqrt(32)

// ---------------------------------------------------------------------------
// prep: kv = src + src_pos_embed ; box corners from reference_points
// ---------------------------------------------------------------------------
__global__ __launch_bounds__(256) void prep_kernel(
    const float* __restrict__ src, const float* __restrict__ spe,
    float* __restrict__ kv, const float* __restrict__ refp,
    float* __restrict__ boxx, float* __restrict__ boxy)
{
    int i = blockIdx.x * 256 + threadIdx.x;
    if (i < BB * NKV * DMODEL) kv[i] = src[i] + spe[i];
    if (i < BB * NQ) {
        float cx = refp[i * 4 + 0], cy = refp[i * 4 + 1];
        float w  = refp[i * 4 + 2], h  = refp[i * 4 + 3];
        boxx[i * 2 + 0] = cx - 0.5f * w;
        boxx[i * 2 + 1] = cx + 0.5f * w;
        boxy[i * 2 + 0] = cy - 0.5f * h;
        boxy[i * 2 + 1] = cy + 0.5f * h;
    }
}

// ---------------------------------------------------------------------------
// GEMM core: C[M,N] = act(((A [+P if n0<plimit]) @ W^T + bias) * scale)
// ---------------------------------------------------------------------------
__device__ __forceinline__ void gemm_core(
    const float* __restrict__ A, const float* __restrict__ P, int plimit,
    const float* __restrict__ W, const float* __restrict__ bias,
    float* __restrict__ C, int M, int N, int K, float scale, int relu,
    int m0, int n0)
{
    __shared__ float As[16][68];
    __shared__ float Ws[16][68];
    const int t  = threadIdx.x;
    const int tx = t & 15, ty = t >> 4;
    const bool addp = (P != nullptr) && (n0 < plimit);
    const int mm = t >> 2, kc = t & 3;   // staging coords: 64 rows x 4 float4
    float acc[4][4] = {};
    for (int k0 = 0; k0 < K; k0 += 16) {
        {
            int m = m0 + mm;
            float4 va = make_float4(0.f, 0.f, 0.f, 0.f);
            if (m < M) {
                va = *(const float4*)&A[(size_t)m * K + k0 + 4 * kc];
                if (addp) {
                    float4 p4 = *(const float4*)&P[(size_t)m * K + k0 + 4 * kc];
                    va.x += p4.x; va.y += p4.y; va.z += p4.z; va.w += p4.w;
                }
            }
            As[4 * kc + 0][mm] = va.x;
            As[4 * kc + 1][mm] = va.y;
            As[4 * kc + 2][mm] = va.z;
            As[4 * kc + 3][mm] = va.w;
            float4 vw = *(const float4*)&W[(size_t)(n0 + mm) * K + k0 + 4 * kc];
            Ws[4 * kc + 0][mm] = vw.x;
            Ws[4 * kc + 1][mm] = vw.y;
            Ws[4 * kc + 2][mm] = vw.z;
            Ws[4 * kc + 3][mm] = vw.w;
        }
        __syncthreads();
#pragma unroll
        for (int kk = 0; kk < 16; ++kk) {
            float4 a4 = *(const float4*)&As[kk][4 * ty];
            float4 w4 = *(const float4*)&Ws[kk][4 * tx];
            float a[4] = {a4.x, a4.y, a4.z, a4.w};
            float w[4] = {w4.x, w4.y, w4.z, w4.w};
#pragma unroll
            for (int i = 0; i < 4; ++i)
#pragma unroll
                for (int j = 0; j < 4; ++j) acc[i][j] += a[i] * w[j];
        }
        __syncthreads();
    }
#pragma unroll
    for (int i = 0; i < 4; ++i) {
        int m = m0 + 4 * ty + i;
        if (m >= M) continue;
        float4 o4;
        float v0 = (acc[i][0] + bias[n0 + 4 * tx + 0]) * scale;
        float v1 = (acc[i][1] + bias[n0 + 4 * tx + 1]) * scale;
        float v2 = (acc[i][2] + bias[n0 + 4 * tx + 2]) * scale;
        float v3 = (acc[i][3] + bias[n0 + 4 * tx + 3]) * scale;
        if (relu) {
            v0 = fmaxf(v0, 0.f); v1 = fmaxf(v1, 0.f);
            v2 = fmaxf(v2, 0.f); v3 = fmaxf(v3, 0.f);
        }
        o4.x = v0; o4.y = v1; o4.z = v2; o4.w = v3;
        *(float4*)&C[(size_t)m * N + n0 + 4 * tx] = o4;
    }
}

__global__ __launch_bounds__(256) void gemm_bias(
    const float* __restrict__ A, const float* __restrict__ P, int plimit,
    const float* __restrict__ W, const float* __restrict__ bias,
    float* __restrict__ C, int M, int N, int K, float scale, int relu)
{
    gemm_core(A, P, plimit, W, bias, C, M, N, K, scale, relu,
              blockIdx.y * 64, blockIdx.x * 64);
}

// two independent GEMMs (same M,N,K) selected by blockIdx.z
__global__ __launch_bounds__(256) void gemm_dual(
    const float* __restrict__ A0, const float* __restrict__ A1,
    const float* __restrict__ W0, const float* __restrict__ W1,
    const float* __restrict__ b0, const float* __restrict__ b1,
    float* __restrict__ C0, float* __restrict__ C1, int M, int N, int K)
{
    if (blockIdx.z == 0)
        gemm_core(A0, nullptr, 0, W0, b0, C0, M, N, K, 1.f, 0,
                  blockIdx.y * 64, blockIdx.x * 64);
    else
        gemm_core(A1, nullptr, 0, W1, b1, C1, M, N, K, 1.f, 0,
                  blockIdx.y * 64, blockIdx.x * 64);
}

// ---------------------------------------------------------------------------
// LayerNorm(out + t) -> out, one wave per 256-wide row
// ---------------------------------------------------------------------------
__global__ __launch_bounds__(256) void ln_residual(
    float* __restrict__ out, const float* __restrict__ tt,
    const float* __restrict__ w, const float* __restrict__ b, int rows)
{
    const int wid = threadIdx.x >> 6, lane = threadIdx.x & 63;
    const int row = blockIdx.x * 4 + wid;
    if (row >= rows) return;
    const float* orow = out + row * DMODEL;
    const float* trow = tt + row * DMODEL;
    float x[4];
#pragma unroll
    for (int i = 0; i < 4; ++i) x[i] = orow[lane + 64 * i] + trow[lane + 64 * i];
    float s = x[0] + x[1] + x[2] + x[3];
#pragma unroll
    for (int mask = 1; mask < 64; mask <<= 1) s += __shfl_xor(s, mask);
    float mean = s * (1.f / 256.f);
    float vs = 0.f;
#pragma unroll
    for (int i = 0; i < 4; ++i) { float d = x[i] - mean; vs += d * d; }
#pragma unroll
    for (int mask = 1; mask < 64; mask <<= 1) vs += __shfl_xor(vs, mask);
    float r = rsqrtf(vs * (1.f / 256.f) + 1e-5f);
    float* orw = out + row * DMODEL;
#pragma unroll
    for (int i = 0; i < 4; ++i) {
        int c = lane + 64 * i;
        orw[c] = (x[i] - mean) * r * w[c] + b[c];
    }
}

// ---------------------------------------------------------------------------
// RPE MLP v2: one row (axis,b,q,i) per thread; weights staged in LDS.
// grid (150, 2); 256 threads. Writes rx/ry as (B, NHEAD, NQ, 64).
// out[h] = sum_j relu(d0*w1[j,0] + d1*w1[j,1] + b1[j]) * w2[h,j]
// ---------------------------------------------------------------------------
__global__ __launch_bounds__(256) void rpe_kernel(
    const float* __restrict__ boxx, const float* __restrict__ boxy,
    const float* __restrict__ w1x, const float* __restrict__ b1x,
    const float* __restrict__ w2x,
    const float* __restrict__ w1y, const float* __restrict__ b1y,
    const float* __restrict__ w2y,
    float* __restrict__ rx, float* __restrict__ ry)
{
    __shared__ float wb_s[RPEH][4];   // {w1[j,0], w1[j,1], b1[j], 0}   8 KB
    __shared__ float w2_s[RPEH][8];   // W2 transposed                 16 KB

    const int axis = blockIdx.y;
    const float* __restrict__ w1 = axis ? w1y : w1x;
    const float* __restrict__ b1 = axis ? b1y : b1x;
    const float* __restrict__ w2 = axis ? w2y : w2x;   // [8][512]
    const float* __restrict__ bx = axis ? boxy : boxx;
    const int t = threadIdx.x;

    for (int j = t; j < RPEH; j += 256) {
        wb_s[j][0] = w1[2 * j];
        wb_s[j][1] = w1[2 * j + 1];
        wb_s[j][2] = b1[j];
        wb_s[j][3] = 0.f;
#pragma unroll
        for (int h = 0; h < 8; ++h) w2_s[j][h] = w2[h * RPEH + j];
    }
    __syncthreads();

    const int row = blockIdx.x * 256 + t;   // 0..38399
    const int i  = row & 63;
    const int bq = row >> 6;                // 0..599
    const float pos = (i + 0.5f) * 16.0f;
    const float d0 = bx[bq * 2 + 0] - pos;
    const float d1 = bx[bq * 2 + 1] - pos;

    float acc[8];
#pragma unroll
    for (int h = 0; h < 8; ++h) acc[h] = 0.f;

#pragma unroll 4
    for (int j = 0; j < RPEH; ++j) {
        float4 wb = *(const float4*)&wb_s[j][0];
        float hv = fmaxf(fmaf(d0, wb.x, fmaf(d1, wb.y, wb.z)), 0.f);
        float4 a = *(const float4*)&w2_s[j][0];
        float4 c = *(const float4*)&w2_s[j][4];
        acc[0] = fmaf(hv, a.x, acc[0]);
        acc[1] = fmaf(hv, a.y, acc[1]);
        acc[2] = fmaf(hv, a.z, acc[2]);
        acc[3] = fmaf(hv, a.w, acc[3]);
        acc[4] = fmaf(hv, c.x, acc[4]);
        acc[5] = fmaf(hv, c.y, acc[5]);
        acc[6] = fmaf(hv, c.z, acc[6]);
        acc[7] = fmaf(hv, c.w, acc[7]);
    }

    const int b = bq / NQ, q = bq % NQ;
    float* __restrict__ dst = axis ? ry : rx;
#pragma unroll
    for (int h = 0; h < 8; ++h)
        dst[((size_t)(b * NHEAD + h) * NQ + q) * 64 + i] = acc[h];
}

// ---------------------------------------------------------------------------
// Self-attention (full keys, writes normalized O). 8 lanes per q-row.
// ---------------------------------------------------------------------------
__global__ __launch_bounds__(256) void attn_self(
    const float* __restrict__ Q, const float* __restrict__ K,
    const float* __restrict__ V, float* __restrict__ O,
    int nq, int nkeys, float sscale, int ldq, int ldk)
{
    __shared__ float q_s[32][40];
    __shared__ float k_s[64][40];
    __shared__ float v_s[64][40];

    const int t = threadIdx.x;
    const int r = t >> 3, g = t & 7;
    const int bh = blockIdx.y;
    const int b = bh >> 3, h = bh & 7;
    const int q0 = blockIdx.x * 32;

    {
        int rr = t >> 3, d4 = t & 7;
        int qi = q0 + rr;
        float4 v4 = make_float4(0.f, 0.f, 0.f, 0.f);
        if (qi < nq) v4 = *(const float4*)&Q[((size_t)(b * nq + qi)) * ldq + h * HDIM + d4 * 4];
        *(float4*)&q_s[rr][d4 * 4] = v4;
    }
    __syncthreads();

    float qr[32];
#pragma unroll
    for (int d = 0; d < 32; ++d) qr[d] = q_s[r][d];

    float m = -1e30f, l = 0.f;
    float o[32];
#pragma unroll
    for (int d = 0; d < 32; ++d) o[d] = 0.f;

    const int ntiles = (nkeys + 63) >> 6;
    for (int kt = 0; kt < ntiles; ++kt) {
        const int nbase = kt << 6;
        __syncthreads();
        for (int e = t; e < 512; e += 256) {
            int nn = e >> 3, d4 = e & 7;
            int nk = nbase + nn;
            float4 kk4 = make_float4(0.f, 0.f, 0.f, 0.f), vv4 = kk4;
            if (nk < nkeys) {
                kk4 = *(const float4*)&K[((size_t)(b * nkeys + nk)) * ldk + h * HDIM + d4 * 4];
                vv4 = *(const float4*)&V[((size_t)(b * nkeys + nk)) * ldk + h * HDIM + d4 * 4];
            }
            *(float4*)&k_s[nn][d4 * 4] = kk4;
            *(float4*)&v_s[nn][d4 * 4] = vv4;
        }
        __syncthreads();

        float s[8];
        float tmax = -1e30f;
#pragma unroll
        for (int jj = 0; jj < 8; ++jj) {
            int nl = g + (jj << 3);
            int nk = nbase + nl;
            float sv = -1e30f;
            if (nk < nkeys) {
                float acc = 0.f;
#pragma unroll
                for (int d = 0; d < 32; ++d) acc += qr[d] * k_s[nl][d];
                sv = acc * sscale;
            }
            s[jj] = sv;
            tmax = fmaxf(tmax, sv);
        }
        float mn = fmaxf(m, tmax);
        float c = __expf(m - mn);
        l *= c;
#pragma unroll
        for (int d = 0; d < 32; ++d) o[d] *= c;
        m = mn;
#pragma unroll
        for (int jj = 0; jj < 8; ++jj) {
            int nl = g + (jj << 3);
            float p = __expf(s[jj] - m);
            l += p;
#pragma unroll
            for (int d = 0; d < 32; ++d) o[d] += p * v_s[nl][d];
        }
    }

#pragma unroll
    for (int mask = 1; mask < 8; mask <<= 1) {
        float m2 = __shfl_xor(m, mask);
        float l2 = __shfl_xor(l, mask);
        float mn = fmaxf(m, m2);
        float c1 = __expf(m - mn), c2 = __expf(m2 - mn);
        l = l * c1 + l2 * c2;
#pragma unroll
        for (int d = 0; d < 32; ++d) o[d] = o[d] * c1 + __shfl_xor(o[d], mask) * c2;
        m = mn;
    }
    const int qi = q0 + r;
    if (g == 0 && qi < nq) {
        float inv = 1.f / l;
#pragma unroll
        for (int d = 0; d < 32; ++d)
            O[((size_t)(b * nq + qi)) * DMODEL + h * HDIM + d] = o[d] * inv;
    }
}

// ---------------------------------------------------------------------------
// Cross-attention, split over KV: blockIdx.z = split (NSPLIT x 1024 keys).
// ---------------------------------------------------------------------------
__global__ __launch_bounds__(256) void attn_cross_split(
    const float* __restrict__ Q, const float* __restrict__ K,
    const float* __restrict__ V,
    const float* __restrict__ RX, const float* __restrict__ RY,
    float* __restrict__ po, float* __restrict__ pm, float* __restrict__ pl)
{
    __shared__ float q_s[32][40];
    __shared__ float k_s[64][40];
    __shared__ float v_s[64][40];
    __shared__ float rx_s[32][64];
    __shared__ float ry_s[32][64];

    const int t = threadIdx.x;
    const int r = t >> 3, g = t & 7;
    const int bh = blockIdx.y;
    const int b = bh >> 3, h = bh & 7;
    const int q0 = blockIdx.x * 32;
    const int sp = blockIdx.z;
    const int kbase0 = sp * (NKV / NSPLIT);

    {
        int rr = t >> 3, d4 = t & 7;
        int qi = q0 + rr;
        float4 v4 = make_float4(0.f, 0.f, 0.f, 0.f);
        if (qi < NQ) v4 = *(const float4*)&Q[((size_t)(b * NQ + qi)) * DMODEL + h * HDIM + d4 * 4];
        *(float4*)&q_s[rr][d4 * 4] = v4;
    }
    for (int e = t; e < 512; e += 256) {
        int rr = e >> 4, i4 = e & 15;
        int qi = q0 + rr;
        float4 vx = make_float4(0.f, 0.f, 0.f, 0.f), vy = vx;
        if (qi < NQ) {
            vx = *(const float4*)&RX[(((size_t)(b * NHEAD + h) * NQ) + qi) * 64 + i4 * 4];
            vy = *(const float4*)&RY[(((size_t)(b * NHEAD + h) * NQ) + qi) * 64 + i4 * 4];
        }
        *(float4*)&rx_s[rr][i4 * 4] = vx;
        *(float4*)&ry_s[rr][i4 * 4] = vy;
    }
    __syncthreads();

    float qr[32];
#pragma unroll
    for (int d = 0; d < 32; ++d) qr[d] = q_s[r][d];

    float m = -1e30f, l = 0.f;
    float o[32];
#pragma unroll
    for (int d = 0; d < 32; ++d) o[d] = 0.f;

    const int ntiles = (NKV / NSPLIT) >> 6;   // 16
    for (int kt = 0; kt < ntiles; ++kt) {
        const int nbase = kbase0 + (kt << 6);
        __syncthreads();
        for (int e = t; e < 512; e += 256) {
            int nn = e >> 3, d4 = e & 7;
            int nk = nbase + nn;
            float4 kk4 = *(const float4*)&K[((size_t)(b * NKV + nk)) * DMODEL + h * HDIM + d4 * 4];
            float4 vv4 = *(const float4*)&V[((size_t)(b * NKV + nk)) * DMODEL + h * HDIM + d4 * 4];
            *(float4*)&k_s[nn][d4 * 4] = kk4;
            *(float4*)&v_s[nn][d4 * 4] = vv4;
        }
        __syncthreads();

        float s[8];
        float tmax = -1e30f;
#pragma unroll
        for (int jj = 0; jj < 8; ++jj) {
            int nl = g + (jj << 3);
            int nk = nbase + nl;
            float acc = 0.f;
#pragma unroll
            for (int d = 0; d < 32; ++d) acc += qr[d] * k_s[nl][d];
            float sv = acc + ry_s[r][nk >> 6] + rx_s[r][nk & 63];
            s[jj] = sv;
            tmax = fmaxf(tmax, sv);
        }
        float mn = fmaxf(m, tmax);
        float c = __expf(m - mn);
        l *= c;
#pragma unroll
        for (int d = 0; d < 32; ++d) o[d] *= c;
        m = mn;
#pragma unroll
        for (int jj = 0; jj < 8; ++jj) {
            int nl = g + (jj << 3);
            float p = __expf(s[jj] - m);
            l += p;
#pragma unroll
            for (int d = 0; d < 32; ++d) o[d] += p * v_s[nl][d];
        }
    }

#pragma unroll
    for (int mask = 1; mask < 8; mask <<= 1) {
        float m2 = __shfl_xor(m, mask);
        float l2 = __shfl_xor(l, mask);
        float mn = fmaxf(m, m2);
        float c1 = __expf(m - mn), c2 = __expf(m2 - mn);
        l = l * c1 + l2 * c2;
#pragma unroll
        for (int d = 0; d < 32; ++d) o[d] = o[d] * c1 + __shfl_xor(o[d], mask) * c2;
        m = mn;
    }
    const int qi = q0 + r;
    if (g == 0 && qi < NQ) {
        size_t base = ((size_t)(bh * NSPLIT + sp) * NQ + qi);
        pm[base] = m;
        pl[base] = l;
#pragma unroll
        for (int d = 0; d < 32; ++d) po[base * 32 + d] = o[d];
    }
}

// combine NSPLIT partials -> O. 32-lane group per (bh, q).
__global__ __launch_bounds__(256) void attn_combine(
    const float* __restrict__ po, const float* __restrict__ pm,
    const float* __restrict__ pl, float* __restrict__ O)
{
    int gid = blockIdx.x * 8 + (threadIdx.x >> 5);
    int lane = threadIdx.x & 31;
    if (gid >= 16 * NQ) return;
    int bh = gid / NQ, q = gid % NQ;
    int b = bh >> 3, h = bh & 7;
    float M = -1e30f;
#pragma unroll
    for (int s = 0; s < NSPLIT; ++s)
        M = fmaxf(M, pm[(size_t)(bh * NSPLIT + s) * NQ + q]);
    float L = 0.f, acc = 0.f;
#pragma unroll
    for (int s = 0; s < NSPLIT; ++s) {
        size_t base = (size_t)(bh * NSPLIT + s) * NQ + q;
        float w = __expf(pm[base] - M);
        L += pl[base] * w;
        acc += po[base * 32 + lane] * w;
    }
    O[((size_t)(b * NQ + q)) * DMODEL + h * HDIM + lane] = acc / L;
}

// ---------------------------------------------------------------------------
extern "C" void kernel_launch(void* const* d_in, const int* in_sizes, int n_in,
                              void* d_out, int out_size, void* d_ws, size_t ws_size,
                              hipStream_t stream)
{
    const float* tgt   = (const float*)d_in[0];
    const float* qpos  = (const float*)d_in[1];
    const float* refp  = (const float*)d_in[2];
    const float* src   = (const float*)d_in[3];
    const float* spe   = (const float*)d_in[4];
    const float* sa_in_w  = (const float*)d_in[6];
    const float* sa_in_b  = (const float*)d_in[7];
    const float* sa_out_w = (const float*)d_in[8];
    const float* sa_out_b = (const float*)d_in[9];
    const float* n1_w  = (const float*)d_in[10];
    const float* n1_b  = (const float*)d_in[11];
    const float* ca_q_w = (const float*)d_in[12];
    const float* ca_q_b = (const float*)d_in[13];
    const float* ca_k_w = (const float*)d_in[14];
    const float* ca_k_b = (const float*)d_in[15];
    const float* ca_v_w = (const float*)d_in[16];
    const float* ca_v_b = (const float*)d_in[17];
    const float* ca_p_w = (const float*)d_in[18];
    const float* ca_p_b = (const float*)d_in[19];
    const float* cpb1_w1 = (const float*)d_in[20];
    const float* cpb1_b1 = (const float*)d_in[21];
    const float* cpb1_w2 = (const float*)d_in[22];
    const float* cpb2_w1 = (const float*)d_in[23];
    const float* cpb2_b1 = (const float*)d_in[24];
    const float* cpb2_w2 = (const float*)d_in[25];
    const float* n2_w = (const float*)d_in[26];
    const float* n2_b = (const float*)d_in[27];
    const float* ffn_w1 = (const float*)d_in[28];
    const float* ffn_b1 = (const float*)d_in[29];
    const float* ffn_w2 = (const float*)d_in[30];
    const float* ffn_b2 = (const float*)d_in[31];
    const float* n3_w = (const float*)d_in[32];
    const float* n3_b = (const float*)d_in[33];

    float* ws  = (float*)d_ws;
    float* kv   = ws;                 // 2*4096*256
    float* Kc   = kv + 2097152;       // 2*4096*256
    float* Vc   = Kc + 2097152;       // 2*4096*256
    float* outb = Vc + 2097152;       // 600*256
    float* qb   = outb + 153600;      // fused qkv base (600*768 spans qb..vb)
    float* kb   = qb + 153600;
    float* vb   = kb + 153600;
    float* ob   = vb + 153600;
    float* tb   = ob + 153600;
    float* hb   = tb + 153600;        // 600*1024
    float* rx   = hb + 614400;        // 2*8*300*64
    float* ry   = rx + 307200;
    float* boxx = ry + 307200;        // 600*2
    float* boxy = boxx + 1200;
    // attention partials alias FFN scratch (free during attention):
    float* po = hb;                   // 16*NSPLIT*300*32 = 614400 floats
    float* pm = tb;                   // 16*NSPLIT*300 = 19200
    float* pl = tb + 19200;           // 19200
    (void)kb; (void)vb;

    const int M = BB * NQ;            // 600
    const int MK = BB * NKV;          // 8192

    prep_kernel<<<8192, 256, 0, stream>>>(src, spe, kv, refp, boxx, boxy);
    hipMemcpyAsync(outb, tgt, (size_t)M * DMODEL * sizeof(float),
                   hipMemcpyDeviceToDevice, stream);

    for (int l = 0; l < NLAYER; ++l) {
        const float* saw = sa_in_w + (size_t)l * 768 * 256;
        const float* sab = sa_in_b + (size_t)l * 768;

        // ---- self attention ----
        gemm_bias<<<dim3(12, 10), 256, 0, stream>>>(outb, qpos, 512, saw, sab,
                                                    qb, M, 768, 256, 1.f, 0);
        attn_self<<<dim3(10, 16), 256, 0, stream>>>(qb, qb + 256, qb + 512, ob,
                                                    NQ, NQ, ATTN_SCALE, 768, 768);
        gemm_bias<<<dim3(4, 10), 256, 0, stream>>>(ob, nullptr, 0,
            sa_out_w + (size_t)l * 65536, sa_out_b + l * 256, tb, M, 256, 256, 1.f, 0);
        ln_residual<<<150, 256, 0, stream>>>(outb, tb, n1_w + l * 256, n1_b + l * 256, M);

        // ---- cross attention ----
        gemm_bias<<<dim3(4, 10), 256, 0, stream>>>(outb, qpos, 256,
            ca_q_w + (size_t)l * 65536, ca_q_b + l * 256, qb, M, 256, 256, ATTN_SCALE, 0);
        gemm_dual<<<dim3(4, 128, 2), 256, 0, stream>>>(kv, src,
            ca_k_w + (size_t)l * 65536, ca_v_w + (size_t)l * 65536,
            ca_k_b + l * 256, ca_v_b + l * 256, Kc, Vc, MK, 256, 256);
        rpe_kernel<<<dim3(150, 2), 256, 0, stream>>>(boxx, boxy,
            cpb1_w1 + (size_t)l * 1024, cpb1_b1 + (size_t)l * 512, cpb1_w2 + (size_t)l * 4096,
            cpb2_w1 + (size_t)l * 1024, cpb2_b1 + (size_t)l * 512, cpb2_w2 + (size_t)l * 4096,
            rx, ry);
        attn_cross_split<<<dim3(10, 16, NSPLIT), 256, 0, stream>>>(qb, Kc, Vc, rx, ry,
                                                                   po, pm, pl);
        attn_combine<<<600, 256, 0, stream>>>(po, pm, pl, ob);
        gemm_bias<<<dim3(4, 10), 256, 0, stream>>>(ob, nullptr, 0,
            ca_p_w + (size_t)l * 65536, ca_p_b + l * 256, tb, M, 256, 256, 1.f, 0);
        ln_residual<<<150, 256, 0, stream>>>(outb, tb, n2_w + l * 256, n2_b + l * 256, M);

        // ---- FFN ----
        gemm_bias<<<dim3(16, 10), 256, 0, stream>>>(outb, nullptr, 0,
            ffn_w1 + (size_t)l * 262144, ffn_b1 + l * 1024, hb, M, 1024, 256, 1.f, 1);
        gemm_bias<<<dim3(4, 10), 256, 0, stream>>>(hb, nullptr, 0,
            ffn_w2 + (size_t)l * 262144, ffn_b2 + l * 256, tb, M, 256, 1024, 1.f, 0);
        ln_residual<<<150, 256, 0, stream>>>(outb, tb, n3_w + l * 256, n3_b + l * 256, M);
    }

    hipMemcpyAsync(d_out, outb, (size_t)M * DMODEL * sizeof(float),
                   hipMemcpyDeviceToDevice, stream);
}

// Round 4
// 1225.243 us; speedup vs baseline: 3.6120x; 1.5259x over previous
//
#include <hip/hip_runtime.h>
#include <math.h>

#define NQ   300
#define DMODEL 256
#define NHEAD 8
#define HDIM 32
#define BB   2
#define NKV  4096
#define RPEH 512
#define NLAYER 6
#define NSPLIT 4
#define ATTN_SCALE 0.17677669529663687f  // 1/sqrt(32)

typedef short short8 __attribute__((ext_vector_type(8)));
typedef float f32x4 __attribute__((ext_vector_type(4)));

__device__ __forceinline__ short f2bf(float f) {
    union { float fv; unsigned u; } v; v.fv = f;
    unsigned r = v.u + 0x7FFFu + ((v.u >> 16) & 1u);   // RNE
    return (short)(r >> 16);
}

__device__ __forceinline__ short8 pack_bf8(float4 x, float4 y) {
    short8 v;
    v[0] = f2bf(x.x); v[1] = f2bf(x.y); v[2] = f2bf(x.z); v[3] = f2bf(x.w);
    v[4] = f2bf(y.x); v[5] = f2bf(y.y); v[6] = f2bf(y.z); v[7] = f2bf(y.w);
    return v;
}

// ---------------------------------------------------------------------------
// prep: kv = src + src_pos_embed ; box corners from reference_points
// ---------------------------------------------------------------------------
__global__ __launch_bounds__(256) void prep_kernel(
    const float* __restrict__ src, const float* __restrict__ spe,
    float* __restrict__ kv, const float* __restrict__ refp,
    float* __restrict__ boxx, float* __restrict__ boxy)
{
    int i = blockIdx.x * 256 + threadIdx.x;
    if (i < BB * NKV * DMODEL) kv[i] = src[i] + spe[i];
    if (i < BB * NQ) {
        float cx = refp[i * 4 + 0], cy = refp[i * 4 + 1];
        float w  = refp[i * 4 + 2], h  = refp[i * 4 + 3];
        boxx[i * 2 + 0] = cx - 0.5f * w;
        boxx[i * 2 + 1] = cx + 0.5f * w;
        boxy[i * 2 + 0] = cy - 0.5f * h;
        boxy[i * 2 + 1] = cy + 0.5f * h;
    }
}

// ---------------------------------------------------------------------------
// MFMA GEMM core: C[M,N] = act(((A [+P if n0<plimit]) @ W^T + bias) * scale)
// A (M,K) fp32, W (N,K) fp32 -> bf16 LDS staging -> 16x16x32 MFMA, fp32 out.
// Block 256 thr = 4 waves; tile 64x64; wave w owns 32x32 quadrant (wr,wc).
// LDS rows padded to 40 shorts (80 B): 16B-aligned b128 reads, 2-way banks.
// ---------------------------------------------------------------------------
__device__ __forceinline__ void mfma_gemm_core(
    const float* __restrict__ A, const float* __restrict__ P, int plimit,
    const float* __restrict__ W, const float* __restrict__ bias,
    float* __restrict__ C, int M, int N, int K, float scale, int relu,
    int m0, int n0)
{
    __shared__ short A_s[64][40];
    __shared__ short W_s[64][40];
    const int t = threadIdx.x;
    const int lane = t & 63, w = t >> 6;
    const int wr = w >> 1, wc = w & 1;
    const bool addp = (P != nullptr) && (n0 < plimit);
    const int srow = t >> 2, scol = (t & 3) * 8;
    const int l15 = lane & 15, lhi8 = (lane >> 4) * 8;

    f32x4 acc[2][2];
#pragma unroll
    for (int i = 0; i < 2; ++i)
#pragma unroll
        for (int j = 0; j < 2; ++j)
#pragma unroll
            for (int r = 0; r < 4; ++r) acc[i][j][r] = 0.f;

    for (int k0 = 0; k0 < K; k0 += 32) {
        float4 ax = make_float4(0.f, 0.f, 0.f, 0.f), ay = ax;
        {
            int m = m0 + srow;
            if (m < M) {
                const float* ap = &A[(size_t)m * K + k0 + scol];
                ax = *(const float4*)ap;
                ay = *(const float4*)(ap + 4);
                if (addp) {
                    const float* pp = &P[(size_t)m * K + k0 + scol];
                    float4 px = *(const float4*)pp;
                    float4 py = *(const float4*)(pp + 4);
                    ax.x += px.x; ax.y += px.y; ax.z += px.z; ax.w += px.w;
                    ay.x += py.x; ay.y += py.y; ay.z += py.z; ay.w += py.w;
                }
            }
        }
        const float* wp = &W[(size_t)(n0 + srow) * K + k0 + scol];
        float4 wx = *(const float4*)wp;
        float4 wy = *(const float4*)(wp + 4);

        __syncthreads();
        *(short8*)&A_s[srow][scol] = pack_bf8(ax, ay);
        *(short8*)&W_s[srow][scol] = pack_bf8(wx, wy);
        __syncthreads();

        short8 a0 = *(short8*)&A_s[wr * 32 + l15][lhi8];
        short8 a1 = *(short8*)&A_s[wr * 32 + 16 + l15][lhi8];
        short8 b0 = *(short8*)&W_s[wc * 32 + l15][lhi8];
        short8 b1 = *(short8*)&W_s[wc * 32 + 16 + l15][lhi8];
        acc[0][0] = __builtin_amdgcn_mfma_f32_16x16x32_bf16(a0, b0, acc[0][0], 0, 0, 0);
        acc[0][1] = __builtin_amdgcn_mfma_f32_16x16x32_bf16(a0, b1, acc[0][1], 0, 0, 0);
        acc[1][0] = __builtin_amdgcn_mfma_f32_16x16x32_bf16(a1, b0, acc[1][0], 0, 0, 0);
        acc[1][1] = __builtin_amdgcn_mfma_f32_16x16x32_bf16(a1, b1, acc[1][1], 0, 0, 0);
    }

    const int rowb = m0 + wr * 32 + (lane >> 4) * 4;
    const int colb = n0 + wc * 32 + l15;
#pragma unroll
    for (int ni = 0; ni < 2; ++ni) {
        int col = colb + ni * 16;
        float bv = bias[col];
#pragma unroll
        for (int mi = 0; mi < 2; ++mi)
#pragma unroll
            for (int r = 0; r < 4; ++r) {
                int row = rowb + mi * 16 + r;
                if (row < M) {
                    float v = (acc[mi][ni][r] + bv) * scale;
                    if (relu) v = fmaxf(v, 0.f);
                    C[(size_t)row * N + col] = v;
                }
            }
    }
}

__global__ __launch_bounds__(256) void mfma_gemm(
    const float* __restrict__ A, const float* __restrict__ P, int plimit,
    const float* __restrict__ W, const float* __restrict__ bias,
    float* __restrict__ C, int M, int N, int K, float scale, int relu)
{
    mfma_gemm_core(A, P, plimit, W, bias, C, M, N, K, scale, relu,
                   blockIdx.y * 64, blockIdx.x * 64);
}

// two independent GEMMs (same M,N,K) selected by blockIdx.z
__global__ __launch_bounds__(256) void mfma_gemm_dual(
    const float* __restrict__ A0, const float* __restrict__ A1,
    const float* __restrict__ W0, const float* __restrict__ W1,
    const float* __restrict__ b0, const float* __restrict__ b1,
    float* __restrict__ C0, float* __restrict__ C1, int M, int N, int K)
{
    const float* A = blockIdx.z ? A1 : A0;
    const float* W = blockIdx.z ? W1 : W0;
    const float* bs = blockIdx.z ? b1 : b0;
    float* C = blockIdx.z ? C1 : C0;
    mfma_gemm_core(A, nullptr, 0, W, bs, C, M, N, K, 1.f, 0,
                   blockIdx.y * 64, blockIdx.x * 64);
}

// ---------------------------------------------------------------------------
// LayerNorm(out + t) -> out, one wave per 256-wide row
// ---------------------------------------------------------------------------
__global__ __launch_bounds__(256) void ln_residual(
    float* __restrict__ out, const float* __restrict__ tt,
    const float* __restrict__ w, const float* __restrict__ b, int rows)
{
    const int wid = threadIdx.x >> 6, lane = threadIdx.x & 63;
    const int row = blockIdx.x * 4 + wid;
    if (row >= rows) return;
    const float* orow = out + row * DMODEL;
    const float* trow = tt + row * DMODEL;
    float x[4];
#pragma unroll
    for (int i = 0; i < 4; ++i) x[i] = orow[lane + 64 * i] + trow[lane + 64 * i];
    float s = x[0] + x[1] + x[2] + x[3];
#pragma unroll
    for (int mask = 1; mask < 64; mask <<= 1) s += __shfl_xor(s, mask);
    float mean = s * (1.f / 256.f);
    float vs = 0.f;
#pragma unroll
    for (int i = 0; i < 4; ++i) { float d = x[i] - mean; vs += d * d; }
#pragma unroll
    for (int mask = 1; mask < 64; mask <<= 1) vs += __shfl_xor(vs, mask);
    float r = rsqrtf(vs * (1.f / 256.f) + 1e-5f);
    float* orw = out + row * DMODEL;
#pragma unroll
    for (int i = 0; i < 4; ++i) {
        int c = lane + 64 * i;
        orw[c] = (x[i] - mean) * r * w[c] + b[c];
    }
}

// ---------------------------------------------------------------------------
// RPE MLP: one row (axis,b,q,i) per thread; weights staged in LDS.
// grid (150, 2); 256 threads. Writes rx/ry as (B, NHEAD, NQ, 64).
// ---------------------------------------------------------------------------
__global__ __launch_bounds__(256) void rpe_kernel(
    const float* __restrict__ boxx, const float* __restrict__ boxy,
    const float* __restrict__ w1x, const float* __restrict__ b1x,
    const float* __restrict__ w2x,
    const float* __restrict__ w1y, const float* __restrict__ b1y,
    const float* __restrict__ w2y,
    float* __restrict__ rx, float* __restrict__ ry)
{
    __shared__ float wb_s[RPEH][4];
    __shared__ float w2_s[RPEH][8];

    const int axis = blockIdx.y;
    const float* __restrict__ w1 = axis ? w1y : w1x;
    const float* __restrict__ b1 = axis ? b1y : b1x;
    const float* __restrict__ w2 = axis ? w2y : w2x;
    const float* __restrict__ bx = axis ? boxy : boxx;
    const int t = threadIdx.x;

    for (int j = t; j < RPEH; j += 256) {
        wb_s[j][0] = w1[2 * j];
        wb_s[j][1] = w1[2 * j + 1];
        wb_s[j][2] = b1[j];
        wb_s[j][3] = 0.f;
#pragma unroll
        for (int h = 0; h < 8; ++h) w2_s[j][h] = w2[h * RPEH + j];
    }
    __syncthreads();

    const int row = blockIdx.x * 256 + t;
    const int i  = row & 63;
    const int bq = row >> 6;
    const float pos = (i + 0.5f) * 16.0f;
    const float d0 = bx[bq * 2 + 0] - pos;
    const float d1 = bx[bq * 2 + 1] - pos;

    float acc[8];
#pragma unroll
    for (int h = 0; h < 8; ++h) acc[h] = 0.f;

#pragma unroll 4
    for (int j = 0; j < RPEH; ++j) {
        float4 wb = *(const float4*)&wb_s[j][0];
        float hv = fmaxf(fmaf(d0, wb.x, fmaf(d1, wb.y, wb.z)), 0.f);
        float4 a = *(const float4*)&w2_s[j][0];
        float4 c = *(const float4*)&w2_s[j][4];
        acc[0] = fmaf(hv, a.x, acc[0]);
        acc[1] = fmaf(hv, a.y, acc[1]);
        acc[2] = fmaf(hv, a.z, acc[2]);
        acc[3] = fmaf(hv, a.w, acc[3]);
        acc[4] = fmaf(hv, c.x, acc[4]);
        acc[5] = fmaf(hv, c.y, acc[5]);
        acc[6] = fmaf(hv, c.z, acc[6]);
        acc[7] = fmaf(hv, c.w, acc[7]);
    }

    const int b = bq / NQ, q = bq % NQ;
    float* __restrict__ dst = axis ? ry : rx;
#pragma unroll
    for (int h = 0; h < 8; ++h)
        dst[((size_t)(b * NHEAD + h) * NQ + q) * 64 + i] = acc[h];
}

// ---------------------------------------------------------------------------
// Self-attention (fp32, 300 keys), 8 lanes per q-row.
// ---------------------------------------------------------------------------
__global__ __launch_bounds__(256) void attn_self(
    const float* __restrict__ Q, const float* __restrict__ K,
    const float* __restrict__ V, float* __restrict__ O,
    int nq, int nkeys, float sscale, int ldq, int ldk)
{
    __shared__ float q_s[32][40];
    __shared__ float k_s[64][40];
    __shared__ float v_s[64][40];

    const int t = threadIdx.x;
    const int r = t >> 3, g = t & 7;
    const int bh = blockIdx.y;
    const int b = bh >> 3, h = bh & 7;
    const int q0 = blockIdx.x * 32;

    {
        int rr = t >> 3, d4 = t & 7;
        int qi = q0 + rr;
        float4 v4 = make_float4(0.f, 0.f, 0.f, 0.f);
        if (qi < nq) v4 = *(const float4*)&Q[((size_t)(b * nq + qi)) * ldq + h * HDIM + d4 * 4];
        *(float4*)&q_s[rr][d4 * 4] = v4;
    }
    __syncthreads();

    float qr[32];
#pragma unroll
    for (int d = 0; d < 32; ++d) qr[d] = q_s[r][d];

    float m = -1e30f, l = 0.f;
    float o[32];
#pragma unroll
    for (int d = 0; d < 32; ++d) o[d] = 0.f;

    const int ntiles = (nkeys + 63) >> 6;
    for (int kt = 0; kt < ntiles; ++kt) {
        const int nbase = kt << 6;
        __syncthreads();
        for (int e = t; e < 512; e += 256) {
            int nn = e >> 3, d4 = e & 7;
            int nk = nbase + nn;
            float4 kk4 = make_float4(0.f, 0.f, 0.f, 0.f), vv4 = kk4;
            if (nk < nkeys) {
                kk4 = *(const float4*)&K[((size_t)(b * nkeys + nk)) * ldk + h * HDIM + d4 * 4];
                vv4 = *(const float4*)&V[((size_t)(b * nkeys + nk)) * ldk + h * HDIM + d4 * 4];
            }
            *(float4*)&k_s[nn][d4 * 4] = kk4;
            *(float4*)&v_s[nn][d4 * 4] = vv4;
        }
        __syncthreads();

        float s[8];
        float tmax = -1e30f;
#pragma unroll
        for (int jj = 0; jj < 8; ++jj) {
            int nl = g + (jj << 3);
            int nk = nbase + nl;
            float sv = -1e30f;
            if (nk < nkeys) {
                float acc = 0.f;
#pragma unroll
                for (int d = 0; d < 32; ++d) acc += qr[d] * k_s[nl][d];
                sv = acc * sscale;
            }
            s[jj] = sv;
            tmax = fmaxf(tmax, sv);
        }
        float mn = fmaxf(m, tmax);
        float c = __expf(m - mn);
        l *= c;
#pragma unroll
        for (int d = 0; d < 32; ++d) o[d] *= c;
        m = mn;
#pragma unroll
        for (int jj = 0; jj < 8; ++jj) {
            int nl = g + (jj << 3);
            float p = __expf(s[jj] - m);
            l += p;
#pragma unroll
            for (int d = 0; d < 32; ++d) o[d] += p * v_s[nl][d];
        }
    }

#pragma unroll
    for (int mask = 1; mask < 8; mask <<= 1) {
        float m2 = __shfl_xor(m, mask);
        float l2 = __shfl_xor(l, mask);
        float mn = fmaxf(m, m2);
        float c1 = __expf(m - mn), c2 = __expf(m2 - mn);
        l = l * c1 + l2 * c2;
#pragma unroll
        for (int d = 0; d < 32; ++d) o[d] = o[d] * c1 + __shfl_xor(o[d], mask) * c2;
        m = mn;
    }
    const int qi = q0 + r;
    if (g == 0 && qi < nq) {
        float inv = 1.f / l;
#pragma unroll
        for (int d = 0; d < 32; ++d)
            O[((size_t)(b * nq + qi)) * DMODEL + h * HDIM + d] = o[d] * inv;
    }
}

// ---------------------------------------------------------------------------
// MFMA cross-attention. Block = (qtile 64, bh, split). 4 waves x 16 q-rows.
// S = mfma(Q, K^T) -> online softmax (rows live on (lane>>4)*4+reg) ->
// P through wave-private LDS -> O += mfma(P, V) with V staged transposed.
// RPE: rx depends only on key&63 (regs, loaded once), ry only on key>>6.
// Writes unnormalized partials po/pm/pl (NSPLIT splits), combined later.
// ---------------------------------------------------------------------------
__global__ __launch_bounds__(256) void attn_cross_mfma(
    const float* __restrict__ Q, const float* __restrict__ K,
    const float* __restrict__ V,
    const float* __restrict__ RX, const float* __restrict__ RY,
    float* __restrict__ po, float* __restrict__ pm, float* __restrict__ pl)
{
    __shared__ short Q_s[64][40];
    __shared__ short K_s[64][40];
    __shared__ short V_s[32][72];      // transposed: [d][key], 144B rows
    __shared__ short P_s[4][16][72];   // per-wave P tile [q][key]

    const int t = threadIdx.x;
    const int lane = t & 63, w = t >> 6;
    const int l15 = lane & 15, lhi8 = (lane >> 4) * 8, lhi4 = (lane >> 4) * 4;
    const int bh = blockIdx.y, b = bh >> 3, h = bh & 7;
    const int q0 = blockIdx.x * 64;
    const int sp = blockIdx.z;

    // stage Q tile (64 q x 32 d) as bf16
    {
        int q = t >> 2, kc = (t & 3) * 8;
        int qi = q0 + q;
        float4 x = make_float4(0.f, 0.f, 0.f, 0.f), y = x;
        if (qi < NQ) {
            const float* qp = &Q[((size_t)(b * NQ + qi)) * DMODEL + h * HDIM + kc];
            x = *(const float4*)qp;
            y = *(const float4*)(qp + 4);
        }
        *(short8*)&Q_s[q][kc] = pack_bf8(x, y);
    }

    // per-lane RPE x-values (key&63 periodic) + ry row pointers
    float rxv[4][4];
    const float* ryp[4];
#pragma unroll
    for (int r = 0; r < 4; ++r) {
        int qi = q0 + w * 16 + lhi4 + r;
        int qc = qi < NQ ? qi : NQ - 1;
        const float* rxp = &RX[((size_t)bh * NQ + qc) * 64];
        ryp[r] = &RY[((size_t)bh * NQ + qc) * 64];
#pragma unroll
        for (int nf = 0; nf < 4; ++nf) rxv[r][nf] = rxp[nf * 16 + l15];
    }

    float m_r[4], l_r[4];
    f32x4 oacc[2];
#pragma unroll
    for (int r = 0; r < 4; ++r) { m_r[r] = -1e30f; l_r[r] = 0.f; }
#pragma unroll
    for (int ni = 0; ni < 2; ++ni)
#pragma unroll
        for (int r = 0; r < 4; ++r) oacc[ni][r] = 0.f;

    const int nt = (NKV / NSPLIT) >> 6;   // 16 tiles of 64 keys
    for (int kt = 0; kt < nt; ++kt) {
        const int key0 = sp * (NKV / NSPLIT) + (kt << 6);
        __syncthreads();
        {
            int key = t >> 2, kc = (t & 3) * 8;
            const float* kp = &K[((size_t)(b * NKV + key0 + key)) * DMODEL + h * HDIM + kc];
            float4 kx = *(const float4*)kp;
            float4 ky = *(const float4*)(kp + 4);
            *(short8*)&K_s[key][kc] = pack_bf8(kx, ky);

            const float* vp = &V[((size_t)(b * NKV + key0 + key)) * DMODEL + h * HDIM + kc];
            float4 vx = *(const float4*)vp;
            float4 vy = *(const float4*)(vp + 4);
            V_s[kc + 0][key] = f2bf(vx.x);
            V_s[kc + 1][key] = f2bf(vx.y);
            V_s[kc + 2][key] = f2bf(vx.z);
            V_s[kc + 3][key] = f2bf(vx.w);
            V_s[kc + 4][key] = f2bf(vy.x);
            V_s[kc + 5][key] = f2bf(vy.y);
            V_s[kc + 6][key] = f2bf(vy.z);
            V_s[kc + 7][key] = f2bf(vy.w);
        }
        __syncthreads();

        // scores: S[16q][64k] per wave, 4 MFMA (K=32 = full head dim)
        short8 aq = *(short8*)&Q_s[w * 16 + l15][lhi8];
        f32x4 sacc[4];
#pragma unroll
        for (int nf = 0; nf < 4; ++nf) {
#pragma unroll
            for (int r = 0; r < 4; ++r) sacc[nf][r] = 0.f;
            short8 kb = *(short8*)&K_s[nf * 16 + l15][lhi8];
            sacc[nf] = __builtin_amdgcn_mfma_f32_16x16x32_bf16(aq, kb, sacc[nf], 0, 0, 0);
        }

        const int ktg = key0 >> 6;
        float c_r[4];
#pragma unroll
        for (int r = 0; r < 4; ++r) {
            float ryv = ryp[r][ktg];
            float sv0 = sacc[0][r] + rxv[r][0] + ryv;
            float sv1 = sacc[1][r] + rxv[r][1] + ryv;
            float sv2 = sacc[2][r] + rxv[r][2] + ryv;
            float sv3 = sacc[3][r] + rxv[r][3] + ryv;
            float tmax = fmaxf(fmaxf(sv0, sv1), fmaxf(sv2, sv3));
#pragma unroll
            for (int mask = 1; mask < 16; mask <<= 1)
                tmax = fmaxf(tmax, __shfl_xor(tmax, mask));
            float mn = fmaxf(m_r[r], tmax);
            float cc = __expf(m_r[r] - mn);
            m_r[r] = mn; c_r[r] = cc;
            float p0 = __expf(sv0 - mn), p1 = __expf(sv1 - mn);
            float p2 = __expf(sv2 - mn), p3 = __expf(sv3 - mn);
            float ps = p0 + p1 + p2 + p3;
#pragma unroll
            for (int mask = 1; mask < 16; mask <<= 1) ps += __shfl_xor(ps, mask);
            l_r[r] = l_r[r] * cc + ps;
            P_s[w][lhi4 + r][     l15] = f2bf(p0);
            P_s[w][lhi4 + r][16 + l15] = f2bf(p1);
            P_s[w][lhi4 + r][32 + l15] = f2bf(p2);
            P_s[w][lhi4 + r][48 + l15] = f2bf(p3);
        }
#pragma unroll
        for (int ni = 0; ni < 2; ++ni)
#pragma unroll
            for (int r = 0; r < 4; ++r) oacc[ni][r] *= c_r[r];

        // PV: O[16q][32d] += P[16q][64k] * V[64k][32d], 2 k-chunks of 32
        short8 pa0 = *(short8*)&P_s[w][l15][lhi8];
        short8 pa1 = *(short8*)&P_s[w][l15][32 + lhi8];
#pragma unroll
        for (int ni = 0; ni < 2; ++ni) {
            short8 vb0 = *(short8*)&V_s[ni * 16 + l15][lhi8];
            short8 vb1 = *(short8*)&V_s[ni * 16 + l15][32 + lhi8];
            oacc[ni] = __builtin_amdgcn_mfma_f32_16x16x32_bf16(pa0, vb0, oacc[ni], 0, 0, 0);
            oacc[ni] = __builtin_amdgcn_mfma_f32_16x16x32_bf16(pa1, vb1, oacc[ni], 0, 0, 0);
        }
    }

#pragma unroll
    for (int r = 0; r < 4; ++r) {
        int qi = q0 + w * 16 + lhi4 + r;
        if (qi < NQ) {
            size_t base = ((size_t)(bh * NSPLIT + sp) * NQ + qi);
            if (l15 == 0) { pm[base] = m_r[r]; pl[base] = l_r[r]; }
            po[base * 32 + l15] = oacc[0][r];
            po[base * 32 + 16 + l15] = oacc[1][r];
        }
    }
}

// combine NSPLIT partials -> O. 32-lane group per (bh, q).
__global__ __launch_bounds__(256) void attn_combine(
    const float* __restrict__ po, const float* __restrict__ pm,
    const float* __restrict__ pl, float* __restrict__ O)
{
    int gid = blockIdx.x * 8 + (threadIdx.x >> 5);
    int lane = threadIdx.x & 31;
    if (gid >= 16 * NQ) return;
    int bh = gid / NQ, q = gid % NQ;
    int b = bh >> 3, h = bh & 7;
    float M = -1e30f;
#pragma unroll
    for (int s = 0; s < NSPLIT; ++s)
        M = fmaxf(M, pm[(size_t)(bh * NSPLIT + s) * NQ + q]);
    float L = 0.f, acc = 0.f;
#pragma unroll
    for (int s = 0; s < NSPLIT; ++s) {
        size_t base = (size_t)(bh * NSPLIT + s) * NQ + q;
        float w = __expf(pm[base] - M);
        L += pl[base] * w;
        acc += po[base * 32 + lane] * w;
    }
    O[((size_t)(b * NQ + q)) * DMODEL + h * HDIM + lane] = acc / L;
}

// ---------------------------------------------------------------------------
extern "C" void kernel_launch(void* const* d_in, const int* in_sizes, int n_in,
                              void* d_out, int out_size, void* d_ws, size_t ws_size,
                              hipStream_t stream)
{
    const float* tgt   = (const float*)d_in[0];
    const float* qpos  = (const float*)d_in[1];
    const float* refp  = (const float*)d_in[2];
    const float* src   = (const float*)d_in[3];
    const float* spe   = (const float*)d_in[4];
    const float* sa_in_w  = (const float*)d_in[6];
    const float* sa_in_b  = (const float*)d_in[7];
    const float* sa_out_w = (const float*)d_in[8];
    const float* sa_out_b = (const float*)d_in[9];
    const float* n1_w  = (const float*)d_in[10];
    const float* n1_b  = (const float*)d_in[11];
    const float* ca_q_w = (const float*)d_in[12];
    const float* ca_q_b = (const float*)d_in[13];
    const float* ca_k_w = (const float*)d_in[14];
    const float* ca_k_b = (const float*)d_in[15];
    const float* ca_v_w = (const float*)d_in[16];
    const float* ca_v_b = (const float*)d_in[17];
    const float* ca_p_w = (const float*)d_in[18];
    const float* ca_p_b = (const float*)d_in[19];
    const float* cpb1_w1 = (const float*)d_in[20];
    const float* cpb1_b1 = (const float*)d_in[21];
    const float* cpb1_w2 = (const float*)d_in[22];
    const float* cpb2_w1 = (const float*)d_in[23];
    const float* cpb2_b1 = (const float*)d_in[24];
    const float* cpb2_w2 = (const float*)d_in[25];
    const float* n2_w = (const float*)d_in[26];
    const float* n2_b = (const float*)d_in[27];
    const float* ffn_w1 = (const float*)d_in[28];
    const float* ffn_b1 = (const float*)d_in[29];
    const float* ffn_w2 = (const float*)d_in[30];
    const float* ffn_b2 = (const float*)d_in[31];
    const float* n3_w = (const float*)d_in[32];
    const float* n3_b = (const float*)d_in[33];

    float* ws  = (float*)d_ws;
    float* kv   = ws;                 // 2*4096*256
    float* Kc   = kv + 2097152;
    float* Vc   = Kc + 2097152;
    float* outb = Vc + 2097152;       // 600*256
    float* qb   = outb + 153600;      // fused qkv (600*768 spans qb..vb)
    float* kb   = qb + 153600;
    float* vb   = kb + 153600;
    float* ob   = vb + 153600;
    float* tb   = ob + 153600;
    float* hb   = tb + 153600;        // 600*1024
    float* rx   = hb + 614400;        // 2*8*300*64
    float* ry   = rx + 307200;
    float* boxx = ry + 307200;
    float* boxy = boxx + 1200;
    // attention partials alias FFN scratch:
    float* po = hb;                   // 16*NSPLIT*300*32 = 614400
    float* pm = tb;                   // 19200
    float* pl = tb + 19200;           // 19200
    (void)kb; (void)vb;

    const int M = BB * NQ;            // 600
    const int MK = BB * NKV;          // 8192

    prep_kernel<<<8192, 256, 0, stream>>>(src, spe, kv, refp, boxx, boxy);
    hipMemcpyAsync(outb, tgt, (size_t)M * DMODEL * sizeof(float),
                   hipMemcpyDeviceToDevice, stream);

    for (int l = 0; l < NLAYER; ++l) {
        const float* saw = sa_in_w + (size_t)l * 768 * 256;
        const float* sab = sa_in_b + (size_t)l * 768;

        // ---- self attention ----
        mfma_gemm<<<dim3(12, 10), 256, 0, stream>>>(outb, qpos, 512, saw, sab,
                                                    qb, M, 768, 256, 1.f, 0);
        attn_self<<<dim3(10, 16), 256, 0, stream>>>(qb, qb + 256, qb + 512, ob,
                                                    NQ, NQ, ATTN_SCALE, 768, 768);
        mfma_gemm<<<dim3(4, 10), 256, 0, stream>>>(ob, nullptr, 0,
            sa_out_w + (size_t)l * 65536, sa_out_b + l * 256, tb, M, 256, 256, 1.f, 0);
        ln_residual<<<150, 256, 0, stream>>>(outb, tb, n1_w + l * 256, n1_b + l * 256, M);

        // ---- cross attention ----
        mfma_gemm<<<dim3(4, 10), 256, 0, stream>>>(outb, qpos, 256,
            ca_q_w + (size_t)l * 65536, ca_q_b + l * 256, qb, M, 256, 256, ATTN_SCALE, 0);
        mfma_gemm_dual<<<dim3(4, 128, 2), 256, 0, stream>>>(kv, src,
            ca_k_w + (size_t)l * 65536, ca_v_w + (size_t)l * 65536,
            ca_k_b + l * 256, ca_v_b + l * 256, Kc, Vc, MK, 256, 256);
        rpe_kernel<<<dim3(150, 2), 256, 0, stream>>>(boxx, boxy,
            cpb1_w1 + (size_t)l * 1024, cpb1_b1 + (size_t)l * 512, cpb1_w2 + (size_t)l * 4096,
            cpb2_w1 + (size_t)l * 1024, cpb2_b1 + (size_t)l * 512, cpb2_w2 + (size_t)l * 4096,
            rx, ry);
        attn_cross_mfma<<<dim3(5, 16, NSPLIT), 256, 0, stream>>>(qb, Kc, Vc, rx, ry,
                                                                 po, pm, pl);
        attn_combine<<<600, 256, 0, stream>>>(po, pm, pl, ob);
        mfma_gemm<<<dim3(4, 10), 256, 0, stream>>>(ob, nullptr, 0,
            ca_p_w + (size_t)l * 65536, ca_p_b + l * 256, tb, M, 256, 256, 1.f, 0);
        ln_residual<<<150, 256, 0, stream>>>(outb, tb, n2_w + l * 256, n2_b + l * 256, M);

        // ---- FFN ----
        mfma_gemm<<<dim3(16, 10), 256, 0, stream>>>(outb, nullptr, 0,
            ffn_w1 + (size_t)l * 262144, ffn_b1 + l * 1024, hb, M, 1024, 256, 1.f, 1);
        mfma_gemm<<<dim3(4, 10), 256, 0, stream>>>(hb, nullptr, 0,
            ffn_w2 + (size_t)l * 262144, ffn_b2 + l * 256, tb, M, 256, 1024, 1.f, 0);
        ln_residual<<<150, 256, 0, stream>>>(outb, tb, n3_w + l * 256, n3_b + l * 256, M);
    }

    hipMemcpyAsync(d_out, outb, (size_t)M * DMODEL * sizeof(float),
                   hipMemcpyDeviceToDevice, stream);
}

// Round 5
// 1063.815 us; speedup vs baseline: 4.1601x; 1.1517x over previous
//
#include <hip/hip_runtime.h>
#include <math.h>

#define NQ   300
#define DMODEL 256
#define NHEAD 8
#define HDIM 32
#define BB   2
#define NKV  4096
#define RPEH 512
#define NLAYER 6
#define ATTN_SCALE 0.17677669529663687f  // 1/sqrt(32)

typedef short short8 __attribute__((ext_vector_type(8)));
typedef float f32x4 __attribute__((ext_vector_type(4)));
typedef unsigned short ushort_t;

__device__ __forceinline__ short f2bf(float f) {
    union { float fv; unsigned u; } v; v.fv = f;
    unsigned r = v.u + 0x7FFFu + ((v.u >> 16) & 1u);   // RNE
    return (short)(r >> 16);
}
__device__ __forceinline__ float bf2f(ushort_t u) {
    union { unsigned u; float f; } v; v.u = ((unsigned)u) << 16;
    return v.f;
}

__device__ __forceinline__ short8 pack_bf8(float4 x, float4 y) {
    short8 v;
    v[0] = f2bf(x.x); v[1] = f2bf(x.y); v[2] = f2bf(x.z); v[3] = f2bf(x.w);
    v[4] = f2bf(y.x); v[5] = f2bf(y.y); v[6] = f2bf(y.z); v[7] = f2bf(y.w);
    return v;
}

// ---------------------------------------------------------------------------
// prep: kv = src + src_pos_embed ; box corners from reference_points
// ---------------------------------------------------------------------------
__global__ __launch_bounds__(256) void prep_kernel(
    const float* __restrict__ src, const float* __restrict__ spe,
    float* __restrict__ kv, const float* __restrict__ refp,
    float* __restrict__ boxx, float* __restrict__ boxy)
{
    int i = blockIdx.x * 256 + threadIdx.x;
    if (i < BB * NKV * DMODEL) kv[i] = src[i] + spe[i];
    if (i < BB * NQ) {
        float cx = refp[i * 4 + 0], cy = refp[i * 4 + 1];
        float w  = refp[i * 4 + 2], h  = refp[i * 4 + 3];
        boxx[i * 2 + 0] = cx - 0.5f * w;
        boxx[i * 2 + 1] = cx + 0.5f * w;
        boxy[i * 2 + 0] = cy - 0.5f * h;
        boxy[i * 2 + 1] = cy + 0.5f * h;
    }
}

// ---------------------------------------------------------------------------
// MFMA GEMM core: C[M,N] = act(((A [+P if n0<plimit]) @ W^T + bias) * scale)
// ---------------------------------------------------------------------------
__device__ __forceinline__ void mfma_gemm_core(
    const float* __restrict__ A, const float* __restrict__ P, int plimit,
    const float* __restrict__ W, const float* __restrict__ bias,
    float* __restrict__ C, int M, int N, int K, float scale, int relu,
    int m0, int n0)
{
    __shared__ short A_s[64][40];
    __shared__ short W_s[64][40];
    const int t = threadIdx.x;
    const int lane = t & 63, w = t >> 6;
    const int wr = w >> 1, wc = w & 1;
    const bool addp = (P != nullptr) && (n0 < plimit);
    const int srow = t >> 2, scol = (t & 3) * 8;
    const int l15 = lane & 15, lhi8 = (lane >> 4) * 8;

    f32x4 acc[2][2];
#pragma unroll
    for (int i = 0; i < 2; ++i)
#pragma unroll
        for (int j = 0; j < 2; ++j)
#pragma unroll
            for (int r = 0; r < 4; ++r) acc[i][j][r] = 0.f;

    for (int k0 = 0; k0 < K; k0 += 32) {
        float4 ax = make_float4(0.f, 0.f, 0.f, 0.f), ay = ax;
        {
            int m = m0 + srow;
            if (m < M) {
                const float* ap = &A[(size_t)m * K + k0 + scol];
                ax = *(const float4*)ap;
                ay = *(const float4*)(ap + 4);
                if (addp) {
                    const float* pp = &P[(size_t)m * K + k0 + scol];
                    float4 px = *(const float4*)pp;
                    float4 py = *(const float4*)(pp + 4);
                    ax.x += px.x; ax.y += px.y; ax.z += px.z; ax.w += px.w;
                    ay.x += py.x; ay.y += py.y; ay.z += py.z; ay.w += py.w;
                }
            }
        }
        const float* wp = &W[(size_t)(n0 + srow) * K + k0 + scol];
        float4 wx = *(const float4*)wp;
        float4 wy = *(const float4*)(wp + 4);

        __syncthreads();
        *(short8*)&A_s[srow][scol] = pack_bf8(ax, ay);
        *(short8*)&W_s[srow][scol] = pack_bf8(wx, wy);
        __syncthreads();

        short8 a0 = *(short8*)&A_s[wr * 32 + l15][lhi8];
        short8 a1 = *(short8*)&A_s[wr * 32 + 16 + l15][lhi8];
        short8 b0 = *(short8*)&W_s[wc * 32 + l15][lhi8];
        short8 b1 = *(short8*)&W_s[wc * 32 + 16 + l15][lhi8];
        acc[0][0] = __builtin_amdgcn_mfma_f32_16x16x32_bf16(a0, b0, acc[0][0], 0, 0, 0);
        acc[0][1] = __builtin_amdgcn_mfma_f32_16x16x32_bf16(a0, b1, acc[0][1], 0, 0, 0);
        acc[1][0] = __builtin_amdgcn_mfma_f32_16x16x32_bf16(a1, b0, acc[1][0], 0, 0, 0);
        acc[1][1] = __builtin_amdgcn_mfma_f32_16x16x32_bf16(a1, b1, acc[1][1], 0, 0, 0);
    }

    const int rowb = m0 + wr * 32 + (lane >> 4) * 4;
    const int colb = n0 + wc * 32 + l15;
#pragma unroll
    for (int ni = 0; ni < 2; ++ni) {
        int col = colb + ni * 16;
        float bv = bias[col];
#pragma unroll
        for (int mi = 0; mi < 2; ++mi)
#pragma unroll
            for (int r = 0; r < 4; ++r) {
                int row = rowb + mi * 16 + r;
                if (row < M) {
                    float v = (acc[mi][ni][r] + bv) * scale;
                    if (relu) v = fmaxf(v, 0.f);
                    C[(size_t)row * N + col] = v;
                }
            }
    }
}

__global__ __launch_bounds__(256) void mfma_gemm(
    const float* __restrict__ A, const float* __restrict__ P, int plimit,
    const float* __restrict__ W, const float* __restrict__ bias,
    float* __restrict__ C, int M, int N, int K, float scale, int relu)
{
    mfma_gemm_core(A, P, plimit, W, bias, C, M, N, K, scale, relu,
                   blockIdx.y * 64, blockIdx.x * 64);
}

__global__ __launch_bounds__(256) void mfma_gemm_dual(
    const float* __restrict__ A0, const float* __restrict__ A1,
    const float* __restrict__ W0, const float* __restrict__ W1,
    const float* __restrict__ b0, const float* __restrict__ b1,
    float* __restrict__ C0, float* __restrict__ C1, int M, int N, int K)
{
    const float* A = blockIdx.z ? A1 : A0;
    const float* W = blockIdx.z ? W1 : W0;
    const float* bs = blockIdx.z ? b1 : b0;
    float* C = blockIdx.z ? C1 : C0;
    mfma_gemm_core(A, nullptr, 0, W, bs, C, M, N, K, 1.f, 0,
                   blockIdx.y * 64, blockIdx.x * 64);
}

// ---------------------------------------------------------------------------
// LayerNorm(out + t) -> out, one wave per 256-wide row
// ---------------------------------------------------------------------------
__global__ __launch_bounds__(256) void ln_residual(
    float* __restrict__ out, const float* __restrict__ tt,
    const float* __restrict__ w, const float* __restrict__ b, int rows)
{
    const int wid = threadIdx.x >> 6, lane = threadIdx.x & 63;
    const int row = blockIdx.x * 4 + wid;
    if (row >= rows) return;
    const float* orow = out + row * DMODEL;
    const float* trow = tt + row * DMODEL;
    float x[4];
#pragma unroll
    for (int i = 0; i < 4; ++i) x[i] = orow[lane + 64 * i] + trow[lane + 64 * i];
    float s = x[0] + x[1] + x[2] + x[3];
#pragma unroll
    for (int mask = 1; mask < 64; mask <<= 1) s += __shfl_xor(s, mask);
    float mean = s * (1.f / 256.f);
    float vs = 0.f;
#pragma unroll
    for (int i = 0; i < 4; ++i) { float d = x[i] - mean; vs += d * d; }
#pragma unroll
    for (int mask = 1; mask < 64; mask <<= 1) vs += __shfl_xor(vs, mask);
    float r = rsqrtf(vs * (1.f / 256.f) + 1e-5f);
    float* orw = out + row * DMODEL;
#pragma unroll
    for (int i = 0; i < 4; ++i) {
        int c = lane + 64 * i;
        orw[c] = (x[i] - mean) * r * w[c] + b[c];
    }
}

// ---------------------------------------------------------------------------
// RPE MLP: one row (axis,b,q,i) per thread; weights staged in LDS.
// ---------------------------------------------------------------------------
__global__ __launch_bounds__(256) void rpe_kernel(
    const float* __restrict__ boxx, const float* __restrict__ boxy,
    const float* __restrict__ w1x, const float* __restrict__ b1x,
    const float* __restrict__ w2x,
    const float* __restrict__ w1y, const float* __restrict__ b1y,
    const float* __restrict__ w2y,
    float* __restrict__ rx, float* __restrict__ ry)
{
    __shared__ float wb_s[RPEH][4];
    __shared__ float w2_s[RPEH][8];

    const int axis = blockIdx.y;
    const float* __restrict__ w1 = axis ? w1y : w1x;
    const float* __restrict__ b1 = axis ? b1y : b1x;
    const float* __restrict__ w2 = axis ? w2y : w2x;
    const float* __restrict__ bx = axis ? boxy : boxx;
    const int t = threadIdx.x;

    for (int j = t; j < RPEH; j += 256) {
        wb_s[j][0] = w1[2 * j];
        wb_s[j][1] = w1[2 * j + 1];
        wb_s[j][2] = b1[j];
        wb_s[j][3] = 0.f;
#pragma unroll
        for (int h = 0; h < 8; ++h) w2_s[j][h] = w2[h * RPEH + j];
    }
    __syncthreads();

    const int row = blockIdx.x * 256 + t;
    const int i  = row & 63;
    const int bq = row >> 6;
    const float pos = (i + 0.5f) * 16.0f;
    const float d0 = bx[bq * 2 + 0] - pos;
    const float d1 = bx[bq * 2 + 1] - pos;

    float acc[8];
#pragma unroll
    for (int h = 0; h < 8; ++h) acc[h] = 0.f;

#pragma unroll 4
    for (int j = 0; j < RPEH; ++j) {
        float4 wb = *(const float4*)&wb_s[j][0];
        float hv = fmaxf(fmaf(d0, wb.x, fmaf(d1, wb.y, wb.z)), 0.f);
        float4 a = *(const float4*)&w2_s[j][0];
        float4 c = *(const float4*)&w2_s[j][4];
        acc[0] = fmaf(hv, a.x, acc[0]);
        acc[1] = fmaf(hv, a.y, acc[1]);
        acc[2] = fmaf(hv, a.z, acc[2]);
        acc[3] = fmaf(hv, a.w, acc[3]);
        acc[4] = fmaf(hv, c.x, acc[4]);
        acc[5] = fmaf(hv, c.y, acc[5]);
        acc[6] = fmaf(hv, c.z, acc[6]);
        acc[7] = fmaf(hv, c.w, acc[7]);
    }

    const int b = bq / NQ, q = bq % NQ;
    float* __restrict__ dst = axis ? ry : rx;
#pragma unroll
    for (int h = 0; h < 8; ++h)
        dst[((size_t)(b * NHEAD + h) * NQ + q) * 64 + i] = acc[h];
}

// ---------------------------------------------------------------------------
// Unified MFMA flash attention with split-KV.
// Block = (q-tile 64, bh, split). 4 waves x 16 q-rows. Keys masked vs nkeys.
// HAS_RPE adds rx (key&63) + ry (key>>6) bias from (B,NH,NQ,64) tables.
// sscale applied at Q staging. Writes bf16 partial O + fp32 (m,l).
// ---------------------------------------------------------------------------
template<int HAS_RPE>
__global__ __launch_bounds__(256) void attn_mfma(
    const float* __restrict__ Q, int ldq,
    const float* __restrict__ K, int ldk,
    const float* __restrict__ V, int ldv,
    int nkeys, int kps, float sscale,
    const float* __restrict__ RX, const float* __restrict__ RY,
    ushort_t* __restrict__ po, float* __restrict__ pm, float* __restrict__ pl,
    int nsplit)
{
    __shared__ short Q_s[64][40];
    __shared__ short K_s[64][40];
    __shared__ short V_s[32][72];      // transposed: [d][key]
    __shared__ short P_s[4][16][72];   // per-wave P tile [q][key]

    const int t = threadIdx.x;
    const int lane = t & 63, w = t >> 6;
    const int l15 = lane & 15, lhi8 = (lane >> 4) * 8, lhi4 = (lane >> 4) * 4;
    const int bh = blockIdx.y, b = bh >> 3, h = bh & 7;
    const int q0 = blockIdx.x * 64;
    const int sp = blockIdx.z;

    // stage Q tile (64 q x 32 d) as bf16, scaled
    {
        int q = t >> 2, kc = (t & 3) * 8;
        int qi = q0 + q;
        float4 x = make_float4(0.f, 0.f, 0.f, 0.f), y = x;
        if (qi < NQ) {
            const float* qp = &Q[((size_t)(b * NQ + qi)) * ldq + h * HDIM + kc];
            x = *(const float4*)qp;
            y = *(const float4*)(qp + 4);
            x.x *= sscale; x.y *= sscale; x.z *= sscale; x.w *= sscale;
            y.x *= sscale; y.y *= sscale; y.z *= sscale; y.w *= sscale;
        }
        *(short8*)&Q_s[q][kc] = pack_bf8(x, y);
    }

    // per-lane RPE x-values (period 64 in key) + ry row pointers
    float rxv[4][4];
    const float* ryp[4];
    if (HAS_RPE) {
#pragma unroll
        for (int r = 0; r < 4; ++r) {
            int qi = q0 + w * 16 + lhi4 + r;
            int qc = qi < NQ ? qi : NQ - 1;
            const float* rxp = &RX[((size_t)bh * NQ + qc) * 64];
            ryp[r] = &RY[((size_t)bh * NQ + qc) * 64];
#pragma unroll
            for (int nf = 0; nf < 4; ++nf) rxv[r][nf] = rxp[nf * 16 + l15];
        }
    }

    float m_r[4], l_r[4];
    f32x4 oacc[2];
#pragma unroll
    for (int r = 0; r < 4; ++r) { m_r[r] = -1e30f; l_r[r] = 0.f; }
#pragma unroll
    for (int ni = 0; ni < 2; ++ni)
#pragma unroll
        for (int r = 0; r < 4; ++r) oacc[ni][r] = 0.f;

    const int nt = kps >> 6;
    for (int kt = 0; kt < nt; ++kt) {
        const int key0 = sp * kps + (kt << 6);
        __syncthreads();
        {
            int key = t >> 2, kc = (t & 3) * 8;
            int rk = key0 + key;
            int rkc = rk < nkeys ? rk : nkeys - 1;
            const float* kp = &K[((size_t)(b * nkeys + rkc)) * ldk + h * HDIM + kc];
            float4 kx = *(const float4*)kp;
            float4 ky = *(const float4*)(kp + 4);
            *(short8*)&K_s[key][kc] = pack_bf8(kx, ky);

            const float* vp = &V[((size_t)(b * nkeys + rkc)) * ldv + h * HDIM + kc];
            float4 vx = *(const float4*)vp;
            float4 vy = *(const float4*)(vp + 4);
            V_s[kc + 0][key] = f2bf(vx.x);
            V_s[kc + 1][key] = f2bf(vx.y);
            V_s[kc + 2][key] = f2bf(vx.z);
            V_s[kc + 3][key] = f2bf(vx.w);
            V_s[kc + 4][key] = f2bf(vy.x);
            V_s[kc + 5][key] = f2bf(vy.y);
            V_s[kc + 6][key] = f2bf(vy.z);
            V_s[kc + 7][key] = f2bf(vy.w);
        }
        __syncthreads();

        // scores: S[16q][64k] per wave
        short8 aq = *(short8*)&Q_s[w * 16 + l15][lhi8];
        f32x4 sacc[4];
#pragma unroll
        for (int nf = 0; nf < 4; ++nf) {
#pragma unroll
            for (int r = 0; r < 4; ++r) sacc[nf][r] = 0.f;
            short8 kb = *(short8*)&K_s[nf * 16 + l15][lhi8];
            sacc[nf] = __builtin_amdgcn_mfma_f32_16x16x32_bf16(aq, kb, sacc[nf], 0, 0, 0);
        }

        const int ktg = key0 >> 6;
        const bool kv0 = key0 +      l15 < nkeys;
        const bool kv1 = key0 + 16 + l15 < nkeys;
        const bool kv2 = key0 + 32 + l15 < nkeys;
        const bool kv3 = key0 + 48 + l15 < nkeys;
        float c_r[4];
#pragma unroll
        for (int r = 0; r < 4; ++r) {
            float ryv = HAS_RPE ? ryp[r][ktg] : 0.f;
            float sv0 = sacc[0][r] + ryv, sv1 = sacc[1][r] + ryv;
            float sv2 = sacc[2][r] + ryv, sv3 = sacc[3][r] + ryv;
            if (HAS_RPE) {
                sv0 += rxv[r][0]; sv1 += rxv[r][1];
                sv2 += rxv[r][2]; sv3 += rxv[r][3];
            }
            sv0 = kv0 ? sv0 : -1e30f;
            sv1 = kv1 ? sv1 : -1e30f;
            sv2 = kv2 ? sv2 : -1e30f;
            sv3 = kv3 ? sv3 : -1e30f;
            float tmax = fmaxf(fmaxf(sv0, sv1), fmaxf(sv2, sv3));
#pragma unroll
            for (int mask = 1; mask < 16; mask <<= 1)
                tmax = fmaxf(tmax, __shfl_xor(tmax, mask));
            float mn = fmaxf(m_r[r], tmax);
            float cc = __expf(m_r[r] - mn);
            m_r[r] = mn; c_r[r] = cc;
            float p0 = __expf(sv0 - mn), p1 = __expf(sv1 - mn);
            float p2 = __expf(sv2 - mn), p3 = __expf(sv3 - mn);
            float ps = p0 + p1 + p2 + p3;
#pragma unroll
            for (int mask = 1; mask < 16; mask <<= 1) ps += __shfl_xor(ps, mask);
            l_r[r] = l_r[r] * cc + ps;
            P_s[w][lhi4 + r][     l15] = f2bf(p0);
            P_s[w][lhi4 + r][16 + l15] = f2bf(p1);
            P_s[w][lhi4 + r][32 + l15] = f2bf(p2);
            P_s[w][lhi4 + r][48 + l15] = f2bf(p3);
        }
#pragma unroll
        for (int ni = 0; ni < 2; ++ni)
#pragma unroll
            for (int r = 0; r < 4; ++r) oacc[ni][r] *= c_r[r];

        // PV: O[16q][32d] += P[16q][64k] * V^T[32d][64k]
        short8 pa0 = *(short8*)&P_s[w][l15][lhi8];
        short8 pa1 = *(short8*)&P_s[w][l15][32 + lhi8];
#pragma unroll
        for (int ni = 0; ni < 2; ++ni) {
            short8 vb0 = *(short8*)&V_s[ni * 16 + l15][lhi8];
            short8 vb1 = *(short8*)&V_s[ni * 16 + l15][32 + lhi8];
            oacc[ni] = __builtin_amdgcn_mfma_f32_16x16x32_bf16(pa0, vb0, oacc[ni], 0, 0, 0);
            oacc[ni] = __builtin_amdgcn_mfma_f32_16x16x32_bf16(pa1, vb1, oacc[ni], 0, 0, 0);
        }
    }

#pragma unroll
    for (int r = 0; r < 4; ++r) {
        int qi = q0 + w * 16 + lhi4 + r;
        if (qi < NQ) {
            size_t base = ((size_t)(bh * nsplit + sp) * NQ + qi);
            if (l15 == 0) { pm[base] = m_r[r]; pl[base] = l_r[r]; }
            po[base * 32 + l15] = (ushort_t)f2bf(oacc[0][r]);
            po[base * 32 + 16 + l15] = (ushort_t)f2bf(oacc[1][r]);
        }
    }
}

// combine nsplit partials -> O. 32-lane group per (bh, q).
__global__ __launch_bounds__(256) void attn_combine(
    const ushort_t* __restrict__ po, const float* __restrict__ pm,
    const float* __restrict__ pl, float* __restrict__ O, int nsplit)
{
    int gid = blockIdx.x * 8 + (threadIdx.x >> 5);
    int lane = threadIdx.x & 31;
    if (gid >= 16 * NQ) return;
    int bh = gid / NQ, q = gid % NQ;
    int b = bh >> 3, h = bh & 7;
    float M = -1e30f;
    for (int s = 0; s < nsplit; ++s)
        M = fmaxf(M, pm[(size_t)(bh * nsplit + s) * NQ + q]);
    float L = 0.f, acc = 0.f;
    for (int s = 0; s < nsplit; ++s) {
        size_t base = (size_t)(bh * nsplit + s) * NQ + q;
        float w = __expf(pm[base] - M);
        L += pl[base] * w;
        acc += bf2f(po[base * 32 + lane]) * w;
    }
    O[((size_t)(b * NQ + q)) * DMODEL + h * HDIM + lane] = acc / L;
}

// ---------------------------------------------------------------------------
extern "C" void kernel_launch(void* const* d_in, const int* in_sizes, int n_in,
                              void* d_out, int out_size, void* d_ws, size_t ws_size,
                              hipStream_t stream)
{
    const float* tgt   = (const float*)d_in[0];
    const float* qpos  = (const float*)d_in[1];
    const float* refp  = (const float*)d_in[2];
    const float* src   = (const float*)d_in[3];
    const float* spe   = (const float*)d_in[4];
    const float* sa_in_w  = (const float*)d_in[6];
    const float* sa_in_b  = (const float*)d_in[7];
    const float* sa_out_w = (const float*)d_in[8];
    const float* sa_out_b = (const float*)d_in[9];
    const float* n1_w  = (const float*)d_in[10];
    const float* n1_b  = (const float*)d_in[11];
    const float* ca_q_w = (const float*)d_in[12];
    const float* ca_q_b = (const float*)d_in[13];
    const float* ca_k_w = (const float*)d_in[14];
    const float* ca_k_b = (const float*)d_in[15];
    const float* ca_v_w = (const float*)d_in[16];
    const float* ca_v_b = (const float*)d_in[17];
    const float* ca_p_w = (const float*)d_in[18];
    const float* ca_p_b = (const float*)d_in[19];
    const float* cpb1_w1 = (const float*)d_in[20];
    const float* cpb1_b1 = (const float*)d_in[21];
    const float* cpb1_w2 = (const float*)d_in[22];
    const float* cpb2_w1 = (const float*)d_in[23];
    const float* cpb2_b1 = (const float*)d_in[24];
    const float* cpb2_w2 = (const float*)d_in[25];
    const float* n2_w = (const float*)d_in[26];
    const float* n2_b = (const float*)d_in[27];
    const float* ffn_w1 = (const float*)d_in[28];
    const float* ffn_b1 = (const float*)d_in[29];
    const float* ffn_w2 = (const float*)d_in[30];
    const float* ffn_b2 = (const float*)d_in[31];
    const float* n3_w = (const float*)d_in[32];
    const float* n3_b = (const float*)d_in[33];

    float* ws  = (float*)d_ws;
    float* kv   = ws;                 // 2*4096*256
    float* Kc   = kv + 2097152;
    float* Vc   = Kc + 2097152;
    float* outb = Vc + 2097152;       // 600*256
    float* qb   = outb + 153600;      // fused qkv (600*768 spans qb..vb)
    float* kb   = qb + 153600;
    float* vb   = kb + 153600;
    float* ob   = vb + 153600;
    float* tb   = ob + 153600;
    float* hb   = tb + 153600;        // 600*1024
    float* rx   = hb + 614400;        // 2*8*300*64
    float* ry   = rx + 307200;
    float* boxx = ry + 307200;
    float* boxy = boxx + 1200;
    // attention partials alias scratch free during attention:
    ushort_t* poh = (ushort_t*)hb;    // bf16: up to 16*8*300*32 = 1.23M shorts (fits hb)
    float* pm = tb;                   // up to 16*8*300 = 38400
    float* pl = tb + 38400;
    (void)kb; (void)vb;

    const int M = BB * NQ;            // 600
    const int MK = BB * NKV;          // 8192

    prep_kernel<<<8192, 256, 0, stream>>>(src, spe, kv, refp, boxx, boxy);
    hipMemcpyAsync(outb, tgt, (size_t)M * DMODEL * sizeof(float),
                   hipMemcpyDeviceToDevice, stream);

    for (int l = 0; l < NLAYER; ++l) {
        const float* saw = sa_in_w + (size_t)l * 768 * 256;
        const float* sab = sa_in_b + (size_t)l * 768;

        // ---- self attention ----
        mfma_gemm<<<dim3(12, 10), 256, 0, stream>>>(outb, qpos, 512, saw, sab,
                                                    qb, M, 768, 256, 1.f, 0);
        attn_mfma<0><<<dim3(5, 16, 5), 256, 0, stream>>>(
            qb, 768, qb + 256, 768, qb + 512, 768,
            NQ, 64, ATTN_SCALE, nullptr, nullptr, poh, pm, pl, 5);
        attn_combine<<<600, 256, 0, stream>>>(poh, pm, pl, ob, 5);
        mfma_gemm<<<dim3(4, 10), 256, 0, stream>>>(ob, nullptr, 0,
            sa_out_w + (size_t)l * 65536, sa_out_b + l * 256, tb, M, 256, 256, 1.f, 0);
        ln_residual<<<150, 256, 0, stream>>>(outb, tb, n1_w + l * 256, n1_b + l * 256, M);

        // ---- cross attention ----
        mfma_gemm<<<dim3(4, 10), 256, 0, stream>>>(outb, qpos, 256,
            ca_q_w + (size_t)l * 65536, ca_q_b + l * 256, qb, M, 256, 256, ATTN_SCALE, 0);
        mfma_gemm_dual<<<dim3(4, 128, 2), 256, 0, stream>>>(kv, src,
            ca_k_w + (size_t)l * 65536, ca_v_w + (size_t)l * 65536,
            ca_k_b + l * 256, ca_v_b + l * 256, Kc, Vc, MK, 256, 256);
        rpe_kernel<<<dim3(150, 2), 256, 0, stream>>>(boxx, boxy,
            cpb1_w1 + (size_t)l * 1024, cpb1_b1 + (size_t)l * 512, cpb1_w2 + (size_t)l * 4096,
            cpb2_w1 + (size_t)l * 1024, cpb2_b1 + (size_t)l * 512, cpb2_w2 + (size_t)l * 4096,
            rx, ry);
        attn_mfma<1><<<dim3(5, 16, 8), 256, 0, stream>>>(
            qb, DMODEL, Kc, DMODEL, Vc, DMODEL,
            NKV, 512, 1.f, rx, ry, poh, pm, pl, 8);
        attn_combine<<<600, 256, 0, stream>>>(poh, pm, pl, ob, 8);
        mfma_gemm<<<dim3(4, 10), 256, 0, stream>>>(ob, nullptr, 0,
            ca_p_w + (size_t)l * 65536, ca_p_b + l * 256, tb, M, 256, 256, 1.f, 0);
        ln_residual<<<150, 256, 0, stream>>>(outb, tb, n2_w + l * 256, n2_b + l * 256, M);

        // ---- FFN ----
        mfma_gemm<<<dim3(16, 10), 256, 0, stream>>>(outb, nullptr, 0,
            ffn_w1 + (size_t)l * 262144, ffn_b1 + l * 1024, hb, M, 1024, 256, 1.f, 1);
        mfma_gemm<<<dim3(4, 10), 256, 0, stream>>>(hb, nullptr, 0,
            ffn_w2 + (size_t)l * 262144, ffn_b2 + l * 256, tb, M, 256, 1024, 1.f, 0);
        ln_residual<<<150, 256, 0, stream>>>(outb, tb, n3_w + l * 256, n3_b + l * 256, M);
    }

    hipMemcpyAsync(d_out, outb, (size_t)M * DMODEL * sizeof(float),
                   hipMemcpyDeviceToDevice, stream);
}

// Round 6
// 1012.079 us; speedup vs baseline: 4.3728x; 1.0511x over previous
//
#include <hip/hip_runtime.h>
#include <math.h>

#define NQ   300
#define DMODEL 256
#define NHEAD 8
#define HDIM 32
#define BB   2
#define NKV  4096
#define RPEH 512
#define NLAYER 6
#define ATTN_SCALE 0.17677669529663687f  // 1/sqrt(32)

typedef short short8 __attribute__((ext_vector_type(8)));
typedef float f32x4 __attribute__((ext_vector_type(4)));
typedef unsigned short ushort_t;

__device__ __forceinline__ short f2bf(float f) {
    union { float fv; unsigned u; } v; v.fv = f;
    unsigned r = v.u + 0x7FFFu + ((v.u >> 16) & 1u);   // RNE
    return (short)(r >> 16);
}
__device__ __forceinline__ float bf2f(ushort_t u) {
    union { unsigned u; float f; } v; v.u = ((unsigned)u) << 16;
    return v.f;
}
__device__ __forceinline__ short8 pack_bf8(float4 x, float4 y) {
    short8 v;
    v[0] = f2bf(x.x); v[1] = f2bf(x.y); v[2] = f2bf(x.z); v[3] = f2bf(x.w);
    v[4] = f2bf(y.x); v[5] = f2bf(y.y); v[6] = f2bf(y.z); v[7] = f2bf(y.w);
    return v;
}

// ---------------------------------------------------------------------------
// prep: kv = src + src_pos_embed ; box corners from reference_points
// ---------------------------------------------------------------------------
__global__ __launch_bounds__(256) void prep_kernel(
    const float* __restrict__ src, const float* __restrict__ spe,
    float* __restrict__ kv, const float* __restrict__ refp,
    float* __restrict__ boxx, float* __restrict__ boxy)
{
    int i = blockIdx.x * 256 + threadIdx.x;
    if (i < BB * NKV * DMODEL) kv[i] = src[i] + spe[i];
    if (i < BB * NQ) {
        float cx = refp[i * 4 + 0], cy = refp[i * 4 + 1];
        float w  = refp[i * 4 + 2], h  = refp[i * 4 + 3];
        boxx[i * 2 + 0] = cx - 0.5f * w;
        boxx[i * 2 + 1] = cx + 0.5f * w;
        boxy[i * 2 + 0] = cy - 0.5f * h;
        boxy[i * 2 + 1] = cy + 0.5f * h;
    }
}

// ---------------------------------------------------------------------------
// Templated MFMA GEMM core.
// A: fp32 (A_BF16=0, optional +P for n0<plimit) or bf16 (A_BF16=1).
// W: fp32 (N,K). Out: fp32 or bf16. Epilogue: v=acc+bias; if(col<slimit)v*=scale;
// 64x64 tile, 4 waves, BK=32, 16x16x32 bf16 MFMA.
// ---------------------------------------------------------------------------
template<int A_BF16, int OUT_BF16, int RELU>
__device__ __forceinline__ void gemm_core_t(
    const void* __restrict__ Av, const float* __restrict__ P, int plimit,
    const float* __restrict__ W, const float* __restrict__ bias,
    void* __restrict__ Cv, int M, int N, int K, float scale, int slimit,
    int m0, int n0)
{
    __shared__ short A_s[64][40];
    __shared__ short W_s[64][40];
    const int t = threadIdx.x;
    const int lane = t & 63, w = t >> 6;
    const int wr = w >> 1, wc = w & 1;
    const bool addp = (!A_BF16) && (P != nullptr) && (n0 < plimit);
    const int srow = t >> 2, scol = (t & 3) * 8;
    const int l15 = lane & 15, lhi8 = (lane >> 4) * 8;

    f32x4 acc[2][2];
#pragma unroll
    for (int i = 0; i < 2; ++i)
#pragma unroll
        for (int j = 0; j < 2; ++j)
#pragma unroll
            for (int r = 0; r < 4; ++r) acc[i][j][r] = 0.f;

    for (int k0 = 0; k0 < K; k0 += 32) {
        short8 apack;
        if (A_BF16) {
            const ushort_t* A16 = (const ushort_t*)Av;
            int m = m0 + srow;
            if (m < M) apack = *(const short8*)&A16[(size_t)m * K + k0 + scol];
            else { short8 z = {0,0,0,0,0,0,0,0}; apack = z; }
        } else {
            const float* A = (const float*)Av;
            float4 ax = make_float4(0.f, 0.f, 0.f, 0.f), ay = ax;
            int m = m0 + srow;
            if (m < M) {
                const float* ap = &A[(size_t)m * K + k0 + scol];
                ax = *(const float4*)ap;
                ay = *(const float4*)(ap + 4);
                if (addp) {
                    const float* pp = &P[(size_t)m * K + k0 + scol];
                    float4 px = *(const float4*)pp;
                    float4 py = *(const float4*)(pp + 4);
                    ax.x += px.x; ax.y += px.y; ax.z += px.z; ax.w += px.w;
                    ay.x += py.x; ay.y += py.y; ay.z += py.z; ay.w += py.w;
                }
            }
            apack = pack_bf8(ax, ay);
        }
        const float* wp = &W[(size_t)(n0 + srow) * K + k0 + scol];
        float4 wx = *(const float4*)wp;
        float4 wy = *(const float4*)(wp + 4);

        __syncthreads();
        *(short8*)&A_s[srow][scol] = apack;
        *(short8*)&W_s[srow][scol] = pack_bf8(wx, wy);
        __syncthreads();

        short8 a0 = *(short8*)&A_s[wr * 32 + l15][lhi8];
        short8 a1 = *(short8*)&A_s[wr * 32 + 16 + l15][lhi8];
        short8 b0 = *(short8*)&W_s[wc * 32 + l15][lhi8];
        short8 b1 = *(short8*)&W_s[wc * 32 + 16 + l15][lhi8];
        acc[0][0] = __builtin_amdgcn_mfma_f32_16x16x32_bf16(a0, b0, acc[0][0], 0, 0, 0);
        acc[0][1] = __builtin_amdgcn_mfma_f32_16x16x32_bf16(a0, b1, acc[0][1], 0, 0, 0);
        acc[1][0] = __builtin_amdgcn_mfma_f32_16x16x32_bf16(a1, b0, acc[1][0], 0, 0, 0);
        acc[1][1] = __builtin_amdgcn_mfma_f32_16x16x32_bf16(a1, b1, acc[1][1], 0, 0, 0);
    }

    const int rowb = m0 + wr * 32 + (lane >> 4) * 4;
    const int colb = n0 + wc * 32 + l15;
#pragma unroll
    for (int ni = 0; ni < 2; ++ni) {
        int col = colb + ni * 16;
        float bv = bias[col];
#pragma unroll
        for (int mi = 0; mi < 2; ++mi)
#pragma unroll
            for (int r = 0; r < 4; ++r) {
                int row = rowb + mi * 16 + r;
                if (row < M) {
                    float v = acc[mi][ni][r] + bv;
                    if (col < slimit) v *= scale;
                    if (RELU) v = fmaxf(v, 0.f);
                    if (OUT_BF16)
                        ((ushort_t*)Cv)[(size_t)row * N + col] = (ushort_t)f2bf(v);
                    else
                        ((float*)Cv)[(size_t)row * N + col] = v;
                }
            }
    }
}

template<int A_BF16, int OUT_BF16, int RELU>
__global__ __launch_bounds__(256) void mfma_gemm_t(
    const void* __restrict__ Av, const float* __restrict__ P, int plimit,
    const float* __restrict__ W, const float* __restrict__ bias,
    void* __restrict__ Cv, int M, int N, int K, float scale, int slimit)
{
    gemm_core_t<A_BF16, OUT_BF16, RELU>(Av, P, plimit, W, bias, Cv,
                                        M, N, K, scale, slimit,
                                        blockIdx.y * 64, blockIdx.x * 64);
}

// all 6 layers' K/V projections in one launch; z = layer*2 + (0:K,1:V)
__global__ __launch_bounds__(256) void mfma_gemm_kv_all(
    const float* __restrict__ kv, const float* __restrict__ src,
    const float* __restrict__ ca_k_w, const float* __restrict__ ca_v_w,
    const float* __restrict__ ca_k_b, const float* __restrict__ ca_v_b,
    ushort_t* __restrict__ Kcb, ushort_t* __restrict__ Vcb)
{
    const int z = blockIdx.z, l = z >> 1, sel = z & 1;
    const float* A = sel ? src : kv;
    const float* W = (sel ? ca_v_w : ca_k_w) + (size_t)l * 65536;
    const float* bias = (sel ? ca_v_b : ca_k_b) + l * 256;
    ushort_t* C = (sel ? Vcb : Kcb) + (size_t)l * (BB * NKV * DMODEL);
    gemm_core_t<0, 1, 0>(A, nullptr, 0, W, bias, C,
                         BB * NKV, DMODEL, DMODEL, 1.f, 0,
                         blockIdx.y * 64, blockIdx.x * 64);
}

// ---------------------------------------------------------------------------
// LayerNorm(out + t) -> out, one wave per 256-wide row
// ---------------------------------------------------------------------------
__global__ __launch_bounds__(256) void ln_residual(
    float* __restrict__ out, const float* __restrict__ tt,
    const float* __restrict__ w, const float* __restrict__ b, int rows)
{
    const int wid = threadIdx.x >> 6, lane = threadIdx.x & 63;
    const int row = blockIdx.x * 4 + wid;
    if (row >= rows) return;
    const float* orow = out + row * DMODEL;
    const float* trow = tt + row * DMODEL;
    float x[4];
#pragma unroll
    for (int i = 0; i < 4; ++i) x[i] = orow[lane + 64 * i] + trow[lane + 64 * i];
    float s = x[0] + x[1] + x[2] + x[3];
#pragma unroll
    for (int mask = 1; mask < 64; mask <<= 1) s += __shfl_xor(s, mask);
    float mean = s * (1.f / 256.f);
    float vs = 0.f;
#pragma unroll
    for (int i = 0; i < 4; ++i) { float d = x[i] - mean; vs += d * d; }
#pragma unroll
    for (int mask = 1; mask < 64; mask <<= 1) vs += __shfl_xor(vs, mask);
    float r = rsqrtf(vs * (1.f / 256.f) + 1e-5f);
    float* orw = out + row * DMODEL;
#pragma unroll
    for (int i = 0; i < 4; ++i) {
        int c = lane + 64 * i;
        orw[c] = (x[i] - mean) * r * w[c] + b[c];
    }
}

// ---------------------------------------------------------------------------
// RPE MLP: one row (axis,b,q,i) per thread; weights staged in LDS.
// ---------------------------------------------------------------------------
__global__ __launch_bounds__(256) void rpe_kernel(
    const float* __restrict__ boxx, const float* __restrict__ boxy,
    const float* __restrict__ w1x, const float* __restrict__ b1x,
    const float* __restrict__ w2x,
    const float* __restrict__ w1y, const float* __restrict__ b1y,
    const float* __restrict__ w2y,
    float* __restrict__ rx, float* __restrict__ ry)
{
    __shared__ float wb_s[RPEH][4];
    __shared__ float w2_s[RPEH][8];

    const int axis = blockIdx.y;
    const float* __restrict__ w1 = axis ? w1y : w1x;
    const float* __restrict__ b1 = axis ? b1y : b1x;
    const float* __restrict__ w2 = axis ? w2y : w2x;
    const float* __restrict__ bx = axis ? boxy : boxx;
    const int t = threadIdx.x;

    for (int j = t; j < RPEH; j += 256) {
        wb_s[j][0] = w1[2 * j];
        wb_s[j][1] = w1[2 * j + 1];
        wb_s[j][2] = b1[j];
        wb_s[j][3] = 0.f;
#pragma unroll
        for (int h = 0; h < 8; ++h) w2_s[j][h] = w2[h * RPEH + j];
    }
    __syncthreads();

    const int row = blockIdx.x * 256 + t;
    const int i  = row & 63;
    const int bq = row >> 6;
    const float pos = (i + 0.5f) * 16.0f;
    const float d0 = bx[bq * 2 + 0] - pos;
    const float d1 = bx[bq * 2 + 1] - pos;

    float acc[8];
#pragma unroll
    for (int h = 0; h < 8; ++h) acc[h] = 0.f;

#pragma unroll 4
    for (int j = 0; j < RPEH; ++j) {
        float4 wb = *(const float4*)&wb_s[j][0];
        float hv = fmaxf(fmaf(d0, wb.x, fmaf(d1, wb.y, wb.z)), 0.f);
        float4 a = *(const float4*)&w2_s[j][0];
        float4 c = *(const float4*)&w2_s[j][4];
        acc[0] = fmaf(hv, a.x, acc[0]);
        acc[1] = fmaf(hv, a.y, acc[1]);
        acc[2] = fmaf(hv, a.z, acc[2]);
        acc[3] = fmaf(hv, a.w, acc[3]);
        acc[4] = fmaf(hv, c.x, acc[4]);
        acc[5] = fmaf(hv, c.y, acc[5]);
        acc[6] = fmaf(hv, c.z, acc[6]);
        acc[7] = fmaf(hv, c.w, acc[7]);
    }

    const int b = bq / NQ, q = bq % NQ;
    float* __restrict__ dst = axis ? ry : rx;
#pragma unroll
    for (int h = 0; h < 8; ++h)
        dst[((size_t)(b * NHEAD + h) * NQ + q) * 64 + i] = acc[h];
}

// ---------------------------------------------------------------------------
// MFMA flash attention, split-KV, bf16 inputs (pre-scaled Q).
// Block = (q-tile 64, bh, split). 4 waves x 16 q-rows. Keys masked vs nkeys.
// ---------------------------------------------------------------------------
template<int HAS_RPE>
__global__ __launch_bounds__(256) void attn_mfma(
    const ushort_t* __restrict__ Q, int ldq,
    const ushort_t* __restrict__ K, int ldk,
    const ushort_t* __restrict__ V, int ldv,
    int nkeys, int kps,
    const float* __restrict__ RX, const float* __restrict__ RY,
    ushort_t* __restrict__ po, float* __restrict__ pm, float* __restrict__ pl,
    int nsplit)
{
    __shared__ short Q_s[64][40];
    __shared__ short K_s[64][40];
    __shared__ short V_s[32][72];      // transposed: [d][key]
    __shared__ short P_s[4][16][72];   // per-wave P tile [q][key]

    const int t = threadIdx.x;
    const int lane = t & 63, w = t >> 6;
    const int l15 = lane & 15, lhi8 = (lane >> 4) * 8, lhi4 = (lane >> 4) * 4;
    const int bh = blockIdx.y, b = bh >> 3, h = bh & 7;
    const int q0 = blockIdx.x * 64;
    const int sp = blockIdx.z;

    {
        int q = t >> 2, kc = (t & 3) * 8;
        int qi = q0 + q;
        short8 qv = {0,0,0,0,0,0,0,0};
        if (qi < NQ) qv = *(const short8*)&Q[((size_t)(b * NQ + qi)) * ldq + h * HDIM + kc];
        *(short8*)&Q_s[q][kc] = qv;
    }

    float rxv[4][4];
    const float* ryp[4];
    if (HAS_RPE) {
#pragma unroll
        for (int r = 0; r < 4; ++r) {
            int qi = q0 + w * 16 + lhi4 + r;
            int qc = qi < NQ ? qi : NQ - 1;
            const float* rxp = &RX[((size_t)bh * NQ + qc) * 64];
            ryp[r] = &RY[((size_t)bh * NQ + qc) * 64];
#pragma unroll
            for (int nf = 0; nf < 4; ++nf) rxv[r][nf] = rxp[nf * 16 + l15];
        }
    }

    float m_r[4], l_r[4];
    f32x4 oacc[2];
#pragma unroll
    for (int r = 0; r < 4; ++r) { m_r[r] = -1e30f; l_r[r] = 0.f; }
#pragma unroll
    for (int ni = 0; ni < 2; ++ni)
#pragma unroll
        for (int r = 0; r < 4; ++r) oacc[ni][r] = 0.f;

    const int nt = kps >> 6;
    for (int kt = 0; kt < nt; ++kt) {
        const int key0 = sp * kps + (kt << 6);
        __syncthreads();
        {
            int key = t >> 2, kc = (t & 3) * 8;
            int rk = key0 + key;
            int rkc = rk < nkeys ? rk : nkeys - 1;
            short8 kvv = *(const short8*)&K[((size_t)(b * nkeys + rkc)) * ldk + h * HDIM + kc];
            *(short8*)&K_s[key][kc] = kvv;
            short8 vvv = *(const short8*)&V[((size_t)(b * nkeys + rkc)) * ldv + h * HDIM + kc];
#pragma unroll
            for (int j = 0; j < 8; ++j) V_s[kc + j][key] = vvv[j];
        }
        __syncthreads();

        short8 aq = *(short8*)&Q_s[w * 16 + l15][lhi8];
        f32x4 sacc[4];
#pragma unroll
        for (int nf = 0; nf < 4; ++nf) {
#pragma unroll
            for (int r = 0; r < 4; ++r) sacc[nf][r] = 0.f;
            short8 kb = *(short8*)&K_s[nf * 16 + l15][lhi8];
            sacc[nf] = __builtin_amdgcn_mfma_f32_16x16x32_bf16(aq, kb, sacc[nf], 0, 0, 0);
        }

        const int ktg = key0 >> 6;
        const bool kv0 = key0 +      l15 < nkeys;
        const bool kv1 = key0 + 16 + l15 < nkeys;
        const bool kv2 = key0 + 32 + l15 < nkeys;
        const bool kv3 = key0 + 48 + l15 < nkeys;
        float c_r[4];
#pragma unroll
        for (int r = 0; r < 4; ++r) {
            float ryv = HAS_RPE ? ryp[r][ktg] : 0.f;
            float sv0 = sacc[0][r] + ryv, sv1 = sacc[1][r] + ryv;
            float sv2 = sacc[2][r] + ryv, sv3 = sacc[3][r] + ryv;
            if (HAS_RPE) {
                sv0 += rxv[r][0]; sv1 += rxv[r][1];
                sv2 += rxv[r][2]; sv3 += rxv[r][3];
            }
            sv0 = kv0 ? sv0 : -1e30f;
            sv1 = kv1 ? sv1 : -1e30f;
            sv2 = kv2 ? sv2 : -1e30f;
            sv3 = kv3 ? sv3 : -1e30f;
            float tmax = fmaxf(fmaxf(sv0, sv1), fmaxf(sv2, sv3));
#pragma unroll
            for (int mask = 1; mask < 16; mask <<= 1)
                tmax = fmaxf(tmax, __shfl_xor(tmax, mask));
            float mn = fmaxf(m_r[r], tmax);
            float cc = __expf(m_r[r] - mn);
            m_r[r] = mn; c_r[r] = cc;
            float p0 = __expf(sv0 - mn), p1 = __expf(sv1 - mn);
            float p2 = __expf(sv2 - mn), p3 = __expf(sv3 - mn);
            float ps = p0 + p1 + p2 + p3;
#pragma unroll
            for (int mask = 1; mask < 16; mask <<= 1) ps += __shfl_xor(ps, mask);
            l_r[r] = l_r[r] * cc + ps;
            P_s[w][lhi4 + r][     l15] = f2bf(p0);
            P_s[w][lhi4 + r][16 + l15] = f2bf(p1);
            P_s[w][lhi4 + r][32 + l15] = f2bf(p2);
            P_s[w][lhi4 + r][48 + l15] = f2bf(p3);
        }
#pragma unroll
        for (int ni = 0; ni < 2; ++ni)
#pragma unroll
            for (int r = 0; r < 4; ++r) oacc[ni][r] *= c_r[r];

        short8 pa0 = *(short8*)&P_s[w][l15][lhi8];
        short8 pa1 = *(short8*)&P_s[w][l15][32 + lhi8];
#pragma unroll
        for (int ni = 0; ni < 2; ++ni) {
            short8 vb0 = *(short8*)&V_s[ni * 16 + l15][lhi8];
            short8 vb1 = *(short8*)&V_s[ni * 16 + l15][32 + lhi8];
            oacc[ni] = __builtin_amdgcn_mfma_f32_16x16x32_bf16(pa0, vb0, oacc[ni], 0, 0, 0);
            oacc[ni] = __builtin_amdgcn_mfma_f32_16x16x32_bf16(pa1, vb1, oacc[ni], 0, 0, 0);
        }
    }

#pragma unroll
    for (int r = 0; r < 4; ++r) {
        int qi = q0 + w * 16 + lhi4 + r;
        if (qi < NQ) {
            size_t base = ((size_t)(bh * nsplit + sp) * NQ + qi);
            if (l15 == 0) { pm[base] = m_r[r]; pl[base] = l_r[r]; }
            po[base * 32 + l15] = (ushort_t)f2bf(oacc[0][r]);
            po[base * 32 + 16 + l15] = (ushort_t)f2bf(oacc[1][r]);
        }
    }
}

// ---------------------------------------------------------------------------
// Fused split-combine + output projection (N=K=256).
// Phase 1: combine nsplit partials into 64x256 bf16 A in LDS.
// Phase 2: stage full 64x256 W as bf16. One barrier, then 32 MFMA, no syncs.
// ---------------------------------------------------------------------------
__global__ __launch_bounds__(256) void combine_gemm(
    const ushort_t* __restrict__ po, const float* __restrict__ pm,
    const float* __restrict__ pl, int nsplit,
    const float* __restrict__ W, const float* __restrict__ bias,
    float* __restrict__ C, int M)
{
    __shared__ short A_s2[64][264];
    __shared__ short W_s2[64][264];
    const int t = threadIdx.x;
    const int m0 = blockIdx.y * 64, n0 = blockIdx.x * 64;

    // phase 1: combine -> A_s2 (bf16)
    {
        int rloc = t >> 2;
        int row = m0 + rloc;
        int dc = (t & 3) * 64;
        if (row < M) {
            int b = row / NQ, q = row % NQ;
#pragma unroll
            for (int hh = 0; hh < 2; ++hh) {
                int h = (dc >> 5) + hh;
                int bh = b * NHEAD + h;
                float Mx = -1e30f;
                for (int s = 0; s < nsplit; ++s)
                    Mx = fmaxf(Mx, pm[(size_t)(bh * nsplit + s) * NQ + q]);
                float L = 0.f;
                float acc[32];
#pragma unroll
                for (int d = 0; d < 32; ++d) acc[d] = 0.f;
                for (int s = 0; s < nsplit; ++s) {
                    size_t base = (size_t)(bh * nsplit + s) * NQ + q;
                    float wgt = __expf(pm[base] - Mx);
                    L += pl[base] * wgt;
                    const ushort_t* pp = &po[base * 32];
#pragma unroll
                    for (int d = 0; d < 32; ++d) acc[d] += bf2f(pp[d]) * wgt;
                }
                float inv = 1.f / L;
#pragma unroll
                for (int d = 0; d < 32; ++d)
                    A_s2[rloc][dc + hh * 32 + d] = f2bf(acc[d] * inv);
            }
        } else {
#pragma unroll
            for (int d = 0; d < 64; ++d) A_s2[rloc][dc + d] = 0;
        }
    }
    // phase 2: stage full W tile (64 n x 256 k) as bf16
    {
        int r = t >> 2;
#pragma unroll
        for (int c8 = 0; c8 < 8; ++c8) {
            int cc = c8 * 32 + (t & 3) * 8;
            const float* wp = &W[(size_t)(n0 + r) * 256 + cc];
            float4 wx = *(const float4*)wp;
            float4 wy = *(const float4*)(wp + 4);
            *(short8*)&W_s2[r][cc] = pack_bf8(wx, wy);
        }
    }
    __syncthreads();

    const int lane = t & 63, w = t >> 6;
    const int wr = w >> 1, wc = w & 1;
    const int l15 = lane & 15, lhi8 = (lane >> 4) * 8;
    f32x4 acc[2][2];
#pragma unroll
    for (int i = 0; i < 2; ++i)
#pragma unroll
        for (int j = 0; j < 2; ++j)
#pragma unroll
            for (int r = 0; r < 4; ++r) acc[i][j][r] = 0.f;

#pragma unroll
    for (int k0 = 0; k0 < 256; k0 += 32) {
        short8 a0 = *(short8*)&A_s2[wr * 32 + l15][k0 + lhi8];
        short8 a1 = *(short8*)&A_s2[wr * 32 + 16 + l15][k0 + lhi8];
        short8 b0 = *(short8*)&W_s2[wc * 32 + l15][k0 + lhi8];
        short8 b1 = *(short8*)&W_s2[wc * 32 + 16 + l15][k0 + lhi8];
        acc[0][0] = __builtin_amdgcn_mfma_f32_16x16x32_bf16(a0, b0, acc[0][0], 0, 0, 0);
        acc[0][1] = __builtin_amdgcn_mfma_f32_16x16x32_bf16(a0, b1, acc[0][1], 0, 0, 0);
        acc[1][0] = __builtin_amdgcn_mfma_f32_16x16x32_bf16(a1, b0, acc[1][0], 0, 0, 0);
        acc[1][1] = __builtin_amdgcn_mfma_f32_16x16x32_bf16(a1, b1, acc[1][1], 0, 0, 0);
    }

    const int rowb = m0 + wr * 32 + (lane >> 4) * 4;
    const int colb = n0 + wc * 32 + l15;
#pragma unroll
    for (int ni = 0; ni < 2; ++ni) {
        int col = colb + ni * 16;
        float bv = bias[col];
#pragma unroll
        for (int mi = 0; mi < 2; ++mi)
#pragma unroll
            for (int r = 0; r < 4; ++r) {
                int row = rowb + mi * 16 + r;
                if (row < M)
                    C[(size_t)row * 256 + col] = acc[mi][ni][r] + bv;
            }
    }
}

// ---------------------------------------------------------------------------
extern "C" void kernel_launch(void* const* d_in, const int* in_sizes, int n_in,
                              void* d_out, int out_size, void* d_ws, size_t ws_size,
                              hipStream_t stream)
{
    const float* tgt   = (const float*)d_in[0];
    const float* qpos  = (const float*)d_in[1];
    const float* refp  = (const float*)d_in[2];
    const float* src   = (const float*)d_in[3];
    const float* spe   = (const float*)d_in[4];
    const float* sa_in_w  = (const float*)d_in[6];
    const float* sa_in_b  = (const float*)d_in[7];
    const float* sa_out_w = (const float*)d_in[8];
    const float* sa_out_b = (const float*)d_in[9];
    const float* n1_w  = (const float*)d_in[10];
    const float* n1_b  = (const float*)d_in[11];
    const float* ca_q_w = (const float*)d_in[12];
    const float* ca_q_b = (const float*)d_in[13];
    const float* ca_k_w = (const float*)d_in[14];
    const float* ca_k_b = (const float*)d_in[15];
    const float* ca_v_w = (const float*)d_in[16];
    const float* ca_v_b = (const float*)d_in[17];
    const float* ca_p_w = (const float*)d_in[18];
    const float* ca_p_b = (const float*)d_in[19];
    const float* cpb1_w1 = (const float*)d_in[20];
    const float* cpb1_b1 = (const float*)d_in[21];
    const float* cpb1_w2 = (const float*)d_in[22];
    const float* cpb2_w1 = (const float*)d_in[23];
    const float* cpb2_b1 = (const float*)d_in[24];
    const float* cpb2_w2 = (const float*)d_in[25];
    const float* n2_w = (const float*)d_in[26];
    const float* n2_b = (const float*)d_in[27];
    const float* ffn_w1 = (const float*)d_in[28];
    const float* ffn_b1 = (const float*)d_in[29];
    const float* ffn_w2 = (const float*)d_in[30];
    const float* ffn_b2 = (const float*)d_in[31];
    const float* n3_w = (const float*)d_in[32];
    const float* n3_b = (const float*)d_in[33];

    float* ws  = (float*)d_ws;
    float* kv    = ws;                      // 2,097,152
    float* outb  = kv + 2097152;            // 153,600
    float* tb    = outb + 153600;           // 153,600
    float* rx    = tb + 153600;             // 307,200
    float* ry    = rx + 307200;             // 307,200
    float* boxx  = ry + 307200;             // 1,200
    float* boxy  = boxx + 1200;             // 1,200
    float* pm    = boxy + 1200;             // 38,400
    float* pl    = pm + 38400;              // 38,400
    ushort_t* qkvb = (ushort_t*)(pl + 38400);   // 600*768
    ushort_t* qcb  = qkvb + 460800;             // 600*256
    ushort_t* hbb  = qcb + 153600;              // 600*1024
    ushort_t* poh  = hbb + 614400;              // 16*8*300*32
    ushort_t* Kcb  = poh + 1228800;             // 6 * 2*4096*256
    ushort_t* Vcb  = Kcb + 12582912;

    const int M = BB * NQ;            // 600

    prep_kernel<<<8192, 256, 0, stream>>>(src, spe, kv, refp, boxx, boxy);
    hipMemcpyAsync(outb, tgt, (size_t)M * DMODEL * sizeof(float),
                   hipMemcpyDeviceToDevice, stream);

    // all layers' K/V projections (depend only on src/kv) in one launch
    mfma_gemm_kv_all<<<dim3(4, 128, 12), 256, 0, stream>>>(
        kv, src, ca_k_w, ca_v_w, ca_k_b, ca_v_b, Kcb, Vcb);

    for (int l = 0; l < NLAYER; ++l) {
        const float* saw = sa_in_w + (size_t)l * 768 * 256;
        const float* sab = sa_in_b + (size_t)l * 768;

        // ---- self attention ----
        mfma_gemm_t<0,1,0><<<dim3(12, 10), 256, 0, stream>>>(
            outb, qpos, 512, saw, sab, qkvb, M, 768, 256, ATTN_SCALE, 256);
        attn_mfma<0><<<dim3(5, 16, 5), 256, 0, stream>>>(
            qkvb, 768, qkvb + 256, 768, qkvb + 512, 768,
            NQ, 64, nullptr, nullptr, poh, pm, pl, 5);
        combine_gemm<<<dim3(4, 10), 256, 0, stream>>>(
            poh, pm, pl, 5, sa_out_w + (size_t)l * 65536, sa_out_b + l * 256, tb, M);
        ln_residual<<<150, 256, 0, stream>>>(outb, tb, n1_w + l * 256, n1_b + l * 256, M);

        // ---- cross attention ----
        mfma_gemm_t<0,1,0><<<dim3(4, 10), 256, 0, stream>>>(
            outb, qpos, 256, ca_q_w + (size_t)l * 65536, ca_q_b + l * 256,
            qcb, M, 256, 256, ATTN_SCALE, 256);
        rpe_kernel<<<dim3(150, 2), 256, 0, stream>>>(boxx, boxy,
            cpb1_w1 + (size_t)l * 1024, cpb1_b1 + (size_t)l * 512, cpb1_w2 + (size_t)l * 4096,
            cpb2_w1 + (size_t)l * 1024, cpb2_b1 + (size_t)l * 512, cpb2_w2 + (size_t)l * 4096,
            rx, ry);
        attn_mfma<1><<<dim3(5, 16, 8), 256, 0, stream>>>(
            qcb, 256, Kcb + (size_t)l * 2097152, 256, Vcb + (size_t)l * 2097152, 256,
            NKV, 512, rx, ry, poh, pm, pl, 8);
        combine_gemm<<<dim3(4, 10), 256, 0, stream>>>(
            poh, pm, pl, 8, ca_p_w + (size_t)l * 65536, ca_p_b + l * 256, tb, M);
        ln_residual<<<150, 256, 0, stream>>>(outb, tb, n2_w + l * 256, n2_b + l * 256, M);

        // ---- FFN ----
        mfma_gemm_t<0,1,1><<<dim3(16, 10), 256, 0, stream>>>(
            outb, nullptr, 0, ffn_w1 + (size_t)l * 262144, ffn_b1 + l * 1024,
            hbb, M, 1024, 256, 1.f, 0);
        mfma_gemm_t<1,0,0><<<dim3(4, 10), 256, 0, stream>>>(
            hbb, nullptr, 0, ffn_w2 + (size_t)l * 262144, ffn_b2 + l * 256,
            tb, M, 256, 1024, 1.f, 0);
        ln_residual<<<150, 256, 0, stream>>>(outb, tb, n3_w + l * 256, n3_b + l * 256, M);
    }

    hipMemcpyAsync(d_out, outb, (size_t)M * DMODEL * sizeof(float),
                   hipMemcpyDeviceToDevice, stream);
}

// Round 7
// 866.394 us; speedup vs baseline: 5.1080x; 1.1682x over previous
//
#include <hip/hip_runtime.h>
#include <math.h>

#define NQ   300
#define DMODEL 256
#define NHEAD 8
#define HDIM 32
#define BB   2
#define NKV  4096
#define RPEH 512
#define NLAYER 6
#define ATTN_SCALE 0.17677669529663687f  // 1/sqrt(32)

typedef short short8 __attribute__((ext_vector_type(8)));
typedef float f32x4 __attribute__((ext_vector_type(4)));
typedef unsigned short ushort_t;

__device__ __forceinline__ short f2bf(float f) {
    union { float fv; unsigned u; } v; v.fv = f;
    unsigned r = v.u + 0x7FFFu + ((v.u >> 16) & 1u);   // RNE
    return (short)(r >> 16);
}
__device__ __forceinline__ float bf2f(ushort_t u) {
    union { unsigned u; float f; } v; v.u = ((unsigned)u) << 16;
    return v.f;
}
__device__ __forceinline__ short8 pack_bf8(float4 x, float4 y) {
    short8 v;
    v[0] = f2bf(x.x); v[1] = f2bf(x.y); v[2] = f2bf(x.z); v[3] = f2bf(x.w);
    v[4] = f2bf(y.x); v[5] = f2bf(y.y); v[6] = f2bf(y.z); v[7] = f2bf(y.w);
    return v;
}

// ---------------------------------------------------------------------------
// prep: kvb16 = bf16(src+spe); srcb16 = bf16(src); out init (fp32+bf16+q16);
// box corners.
// ---------------------------------------------------------------------------
__global__ __launch_bounds__(256) void prep_kernel(
    const float* __restrict__ src, const float* __restrict__ spe,
    const float* __restrict__ tgt, const float* __restrict__ qpos,
    const float* __restrict__ refp,
    ushort_t* __restrict__ kvb16, ushort_t* __restrict__ srcb16,
    float* __restrict__ outb, ushort_t* __restrict__ ob16,
    ushort_t* __restrict__ oq16,
    float* __restrict__ boxx, float* __restrict__ boxy)
{
    int i = blockIdx.x * 256 + threadIdx.x;
    if (i < BB * NKV * DMODEL) {
        float s = src[i];
        kvb16[i]  = (ushort_t)f2bf(s + spe[i]);
        srcb16[i] = (ushort_t)f2bf(s);
    }
    if (i < BB * NQ * DMODEL) {
        float tv = tgt[i];
        outb[i] = tv;
        ob16[i] = (ushort_t)f2bf(tv);
        oq16[i] = (ushort_t)f2bf(tv + qpos[i]);
    }
    if (i < BB * NQ) {
        float cx = refp[i * 4 + 0], cy = refp[i * 4 + 1];
        float w  = refp[i * 4 + 2], h  = refp[i * 4 + 3];
        boxx[i * 2 + 0] = cx - 0.5f * w;
        boxx[i * 2 + 1] = cx + 0.5f * w;
        boxy[i * 2 + 0] = cy - 0.5f * h;
        boxy[i * 2 + 1] = cy + 0.5f * h;
    }
}

// ---------------------------------------------------------------------------
// wconv: convert all GEMM weights fp32 -> bf16 into one ws region.
// Order: sain(1179648) saout(393216) caq cak cav cap(393216 ea) ffn1 ffn2(1572864 ea)
// ---------------------------------------------------------------------------
__global__ __launch_bounds__(256) void wconv_kernel(
    const float* __restrict__ sain, const float* __restrict__ saout,
    const float* __restrict__ caq, const float* __restrict__ cak,
    const float* __restrict__ cav, const float* __restrict__ cap,
    const float* __restrict__ f1, const float* __restrict__ f2,
    ushort_t* __restrict__ dst)
{
    size_t i = ((size_t)blockIdx.x * 256 + threadIdx.x) * 8;
    if (i >= 6291456) return;
    const float* s; size_t off;
    if      (i < 1179648) { s = sain;  off = i; }
    else if (i < 1572864) { s = saout; off = i - 1179648; }
    else if (i < 1966080) { s = caq;   off = i - 1572864; }
    else if (i < 2359296) { s = cak;   off = i - 1966080; }
    else if (i < 2752512) { s = cav;   off = i - 2359296; }
    else if (i < 3145728) { s = cap;   off = i - 2752512; }
    else if (i < 4718592) { s = f1;    off = i - 3145728; }
    else                  { s = f2;    off = i - 4718592; }
    float4 x = *(const float4*)&s[off];
    float4 y = *(const float4*)&s[off + 4];
    *(short8*)&dst[i] = pack_bf8(x, y);
}

// ---------------------------------------------------------------------------
// kv_mega: all 6 layers' K/V projections. grid (4 n, 128 m, 2 sel).
// A-tile staged in LDS once (bf16); loop 6 layers with direct-global W frags.
// ---------------------------------------------------------------------------
__global__ __launch_bounds__(256) void kv_mega(
    const ushort_t* __restrict__ kvb16, const ushort_t* __restrict__ srcb16,
    const ushort_t* __restrict__ Wk, const ushort_t* __restrict__ Wv,
    const float* __restrict__ kbias, const float* __restrict__ vbias,
    ushort_t* __restrict__ Kcb, ushort_t* __restrict__ Vcb)
{
    __shared__ short A_s[64][264];
    const int t = threadIdx.x;
    const int lane = t & 63, w = t >> 6;
    const int wr = w >> 1, wc = w & 1;
    const int l15 = lane & 15, lhi8 = (lane >> 4) * 8;
    const int n0 = blockIdx.x * 64;
    const int m0 = blockIdx.y * 64;
    const int sel = blockIdx.z;
    const ushort_t* A  = sel ? srcb16 : kvb16;
    const ushort_t* Wb = sel ? Wv : Wk;
    const float* bb    = sel ? vbias : kbias;
    ushort_t* Cb       = sel ? Vcb : Kcb;

    {
        int row = t >> 2, c0 = (t & 3) * 64;
        const ushort_t* ap = &A[(size_t)(m0 + row) * 256 + c0];
#pragma unroll
        for (int c8 = 0; c8 < 8; ++c8)
            *(short8*)&A_s[row][c0 + c8 * 8] = *(const short8*)(ap + c8 * 8);
    }
    __syncthreads();

    const int ar0 = wr * 32 + l15, ar1 = ar0 + 16;
    const int rowb = m0 + wr * 32 + (lane >> 4) * 4;
    const int colb = n0 + wc * 32 + l15;

    for (int l = 0; l < NLAYER; ++l) {
        const ushort_t* wp0 = &Wb[(size_t)l * 65536 + (size_t)(n0 + wc * 32 + l15) * 256 + lhi8];
        const ushort_t* wp1 = wp0 + 16 * 256;
        f32x4 acc[2][2];
#pragma unroll
        for (int i = 0; i < 2; ++i)
#pragma unroll
            for (int j = 0; j < 2; ++j)
#pragma unroll
                for (int r = 0; r < 4; ++r) acc[i][j][r] = 0.f;
#pragma unroll
        for (int k0 = 0; k0 < 256; k0 += 32) {
            short8 a0 = *(short8*)&A_s[ar0][k0 + lhi8];
            short8 a1 = *(short8*)&A_s[ar1][k0 + lhi8];
            short8 b0 = *(const short8*)(wp0 + k0);
            short8 b1 = *(const short8*)(wp1 + k0);
            acc[0][0] = __builtin_amdgcn_mfma_f32_16x16x32_bf16(a0, b0, acc[0][0], 0, 0, 0);
            acc[0][1] = __builtin_amdgcn_mfma_f32_16x16x32_bf16(a0, b1, acc[0][1], 0, 0, 0);
            acc[1][0] = __builtin_amdgcn_mfma_f32_16x16x32_bf16(a1, b0, acc[1][0], 0, 0, 0);
            acc[1][1] = __builtin_amdgcn_mfma_f32_16x16x32_bf16(a1, b1, acc[1][1], 0, 0, 0);
        }
        ushort_t* C = Cb + (size_t)l * (BB * NKV * DMODEL);
        const float* bl = bb + l * 256;
#pragma unroll
        for (int ni = 0; ni < 2; ++ni) {
            int col = colb + ni * 16;
            float bv = bl[col];
#pragma unroll
            for (int mi = 0; mi < 2; ++mi)
#pragma unroll
                for (int r = 0; r < 4; ++r) {
                    int row = rowb + mi * 16 + r;
                    C[(size_t)row * 256 + col] = (ushort_t)f2bf(acc[mi][ni][r] + bv);
                }
        }
    }
}

// ---------------------------------------------------------------------------
// gemm_direct: LDS-free bf16 GEMM. C = act((A@W^T + bias) [*scale if col<slimit])
// A bf16 (M,lda) chosen per block (A1 if n0<plimit else A2); W bf16 (N,K).
// grid (N/64, ceil(M/64)); 4 waves, 2x2 quadrants, direct global fragments.
// ---------------------------------------------------------------------------
template<int OUT_BF16, int RELU>
__global__ __launch_bounds__(256) void gemm_direct(
    const ushort_t* __restrict__ A1, const ushort_t* __restrict__ A2, int plimit,
    int lda, const ushort_t* __restrict__ W, const float* __restrict__ bias,
    void* __restrict__ Cv, int ldc, int M, int K, float scale, int slimit)
{
    const int t = threadIdx.x;
    const int lane = t & 63, w = t >> 6;
    const int wr = w >> 1, wc = w & 1;
    const int l15 = lane & 15, lhi8 = (lane >> 4) * 8;
    const int m0 = blockIdx.y * 64, n0 = blockIdx.x * 64;
    const ushort_t* A = (n0 < plimit) ? A1 : A2;

    int r0 = m0 + wr * 32 + l15;      if (r0 > M - 1) r0 = M - 1;
    int r1 = m0 + wr * 32 + 16 + l15; if (r1 > M - 1) r1 = M - 1;
    const ushort_t* ap0 = &A[(size_t)r0 * lda + lhi8];
    const ushort_t* ap1 = &A[(size_t)r1 * lda + lhi8];
    const ushort_t* wp0 = &W[(size_t)(n0 + wc * 32 + l15) * K + lhi8];
    const ushort_t* wp1 = wp0 + (size_t)16 * K;

    f32x4 acc[2][2];
#pragma unroll
    for (int i = 0; i < 2; ++i)
#pragma unroll
        for (int j = 0; j < 2; ++j)
#pragma unroll
            for (int r = 0; r < 4; ++r) acc[i][j][r] = 0.f;

    for (int k0 = 0; k0 < K; k0 += 32) {
        short8 a0 = *(const short8*)(ap0 + k0);
        short8 a1 = *(const short8*)(ap1 + k0);
        short8 b0 = *(const short8*)(wp0 + k0);
        short8 b1 = *(const short8*)(wp1 + k0);
        acc[0][0] = __builtin_amdgcn_mfma_f32_16x16x32_bf16(a0, b0, acc[0][0], 0, 0, 0);
        acc[0][1] = __builtin_amdgcn_mfma_f32_16x16x32_bf16(a0, b1, acc[0][1], 0, 0, 0);
        acc[1][0] = __builtin_amdgcn_mfma_f32_16x16x32_bf16(a1, b0, acc[1][0], 0, 0, 0);
        acc[1][1] = __builtin_amdgcn_mfma_f32_16x16x32_bf16(a1, b1, acc[1][1], 0, 0, 0);
    }

    const int rowb = m0 + wr * 32 + (lane >> 4) * 4;
    const int colb = n0 + wc * 32 + l15;
#pragma unroll
    for (int ni = 0; ni < 2; ++ni) {
        int col = colb + ni * 16;
        float bv = bias[col];
#pragma unroll
        for (int mi = 0; mi < 2; ++mi)
#pragma unroll
            for (int r = 0; r < 4; ++r) {
                int row = rowb + mi * 16 + r;
                if (row < M) {
                    float v = acc[mi][ni][r] + bv;
                    if (col < slimit) v *= scale;
                    if (RELU) v = fmaxf(v, 0.f);
                    if (OUT_BF16)
                        ((ushort_t*)Cv)[(size_t)row * ldc + col] = (ushort_t)f2bf(v);
                    else
                        ((float*)Cv)[(size_t)row * ldc + col] = v;
                }
            }
    }
}

// ---------------------------------------------------------------------------
// LayerNorm(out + t) -> outb fp32, ob16 bf16, oq16 = bf16(out + qpos)
// ---------------------------------------------------------------------------
__global__ __launch_bounds__(256) void ln_residual(
    float* __restrict__ out, const float* __restrict__ tt,
    const float* __restrict__ qpos,
    const float* __restrict__ w, const float* __restrict__ b,
    ushort_t* __restrict__ ob16, ushort_t* __restrict__ oq16, int rows)
{
    const int wid = threadIdx.x >> 6, lane = threadIdx.x & 63;
    const int row = blockIdx.x * 4 + wid;
    if (row >= rows) return;
    const float* orow = out + row * DMODEL;
    const float* trow = tt + row * DMODEL;
    float x[4];
#pragma unroll
    for (int i = 0; i < 4; ++i) x[i] = orow[lane + 64 * i] + trow[lane + 64 * i];
    float s = x[0] + x[1] + x[2] + x[3];
#pragma unroll
    for (int mask = 1; mask < 64; mask <<= 1) s += __shfl_xor(s, mask);
    float mean = s * (1.f / 256.f);
    float vs = 0.f;
#pragma unroll
    for (int i = 0; i < 4; ++i) { float d = x[i] - mean; vs += d * d; }
#pragma unroll
    for (int mask = 1; mask < 64; mask <<= 1) vs += __shfl_xor(vs, mask);
    float r = rsqrtf(vs * (1.f / 256.f) + 1e-5f);
    float* orw = out + row * DMODEL;
#pragma unroll
    for (int i = 0; i < 4; ++i) {
        int c = lane + 64 * i;
        float val = (x[i] - mean) * r * w[c] + b[c];
        orw[c] = val;
        ob16[row * DMODEL + c] = (ushort_t)f2bf(val);
        oq16[row * DMODEL + c] = (ushort_t)f2bf(val + qpos[row * DMODEL + c]);
    }
}

// ---------------------------------------------------------------------------
// RPE MLP for ALL layers: grid (150, 2, 6). Writes rx6/ry6 (l, B, NH, NQ, 64).
// ---------------------------------------------------------------------------
__global__ __launch_bounds__(256) void rpe_all(
    const float* __restrict__ boxx, const float* __restrict__ boxy,
    const float* __restrict__ cpb1_w1, const float* __restrict__ cpb1_b1,
    const float* __restrict__ cpb1_w2,
    const float* __restrict__ cpb2_w1, const float* __restrict__ cpb2_b1,
    const float* __restrict__ cpb2_w2,
    float* __restrict__ rx6, float* __restrict__ ry6)
{
    __shared__ float wb_s[RPEH][4];
    __shared__ float w2_s[RPEH][8];

    const int axis = blockIdx.y;
    const int l = blockIdx.z;
    const float* __restrict__ w1 = (axis ? cpb2_w1 : cpb1_w1) + (size_t)l * 1024;
    const float* __restrict__ b1 = (axis ? cpb2_b1 : cpb1_b1) + (size_t)l * 512;
    const float* __restrict__ w2 = (axis ? cpb2_w2 : cpb1_w2) + (size_t)l * 4096;
    const float* __restrict__ bx = axis ? boxy : boxx;
    const int t = threadIdx.x;

    for (int j = t; j < RPEH; j += 256) {
        wb_s[j][0] = w1[2 * j];
        wb_s[j][1] = w1[2 * j + 1];
        wb_s[j][2] = b1[j];
        wb_s[j][3] = 0.f;
#pragma unroll
        for (int h = 0; h < 8; ++h) w2_s[j][h] = w2[h * RPEH + j];
    }
    __syncthreads();

    const int row = blockIdx.x * 256 + t;
    const int i  = row & 63;
    const int bq = row >> 6;
    const float pos = (i + 0.5f) * 16.0f;
    const float d0 = bx[bq * 2 + 0] - pos;
    const float d1 = bx[bq * 2 + 1] - pos;

    float acc[8];
#pragma unroll
    for (int h = 0; h < 8; ++h) acc[h] = 0.f;

#pragma unroll 4
    for (int j = 0; j < RPEH; ++j) {
        float4 wb = *(const float4*)&wb_s[j][0];
        float hv = fmaxf(fmaf(d0, wb.x, fmaf(d1, wb.y, wb.z)), 0.f);
        float4 a = *(const float4*)&w2_s[j][0];
        float4 c = *(const float4*)&w2_s[j][4];
        acc[0] = fmaf(hv, a.x, acc[0]);
        acc[1] = fmaf(hv, a.y, acc[1]);
        acc[2] = fmaf(hv, a.z, acc[2]);
        acc[3] = fmaf(hv, a.w, acc[3]);
        acc[4] = fmaf(hv, c.x, acc[4]);
        acc[5] = fmaf(hv, c.y, acc[5]);
        acc[6] = fmaf(hv, c.z, acc[6]);
        acc[7] = fmaf(hv, c.w, acc[7]);
    }

    const int b = bq / NQ, q = bq % NQ;
    float* __restrict__ dst = (axis ? ry6 : rx6) + (size_t)l * 307200;
#pragma unroll
    for (int h = 0; h < 8; ++h)
        dst[((size_t)(b * NHEAD + h) * NQ + q) * 64 + i] = acc[h];
}

// ---------------------------------------------------------------------------
// MFMA flash attention, split-KV, bf16 inputs (pre-scaled Q).
// ---------------------------------------------------------------------------
template<int HAS_RPE>
__global__ __launch_bounds__(256) void attn_mfma(
    const ushort_t* __restrict__ Q, int ldq,
    const ushort_t* __restrict__ K, int ldk,
    const ushort_t* __restrict__ V, int ldv,
    int nkeys, int kps,
    const float* __restrict__ RX, const float* __restrict__ RY,
    ushort_t* __restrict__ po, float* __restrict__ pm, float* __restrict__ pl,
    int nsplit)
{
    __shared__ short Q_s[64][40];
    __shared__ short K_s[64][40];
    __shared__ short V_s[32][72];      // transposed: [d][key]
    __shared__ short P_s[4][16][72];   // per-wave P tile [q][key]

    const int t = threadIdx.x;
    const int lane = t & 63, w = t >> 6;
    const int l15 = lane & 15, lhi8 = (lane >> 4) * 8, lhi4 = (lane >> 4) * 4;
    const int bh = blockIdx.y, b = bh >> 3, h = bh & 7;
    const int q0 = blockIdx.x * 64;
    const int sp = blockIdx.z;

    {
        int q = t >> 2, kc = (t & 3) * 8;
        int qi = q0 + q;
        short8 qv = {0,0,0,0,0,0,0,0};
        if (qi < NQ) qv = *(const short8*)&Q[((size_t)(b * NQ + qi)) * ldq + h * HDIM + kc];
        *(short8*)&Q_s[q][kc] = qv;
    }

    float rxv[4][4];
    const float* ryp[4];
    if (HAS_RPE) {
#pragma unroll
        for (int r = 0; r < 4; ++r) {
            int qi = q0 + w * 16 + lhi4 + r;
            int qc = qi < NQ ? qi : NQ - 1;
            const float* rxp = &RX[((size_t)bh * NQ + qc) * 64];
            ryp[r] = &RY[((size_t)bh * NQ + qc) * 64];
#pragma unroll
            for (int nf = 0; nf < 4; ++nf) rxv[r][nf] = rxp[nf * 16 + l15];
        }
    }

    float m_r[4], l_r[4];
    f32x4 oacc[2];
#pragma unroll
    for (int r = 0; r < 4; ++r) { m_r[r] = -1e30f; l_r[r] = 0.f; }
#pragma unroll
    for (int ni = 0; ni < 2; ++ni)
#pragma unroll
        for (int r = 0; r < 4; ++r) oacc[ni][r] = 0.f;

    const int nt = kps >> 6;
    for (int kt = 0; kt < nt; ++kt) {
        const int key0 = sp * kps + (kt << 6);
        __syncthreads();
        {
            int key = t >> 2, kc = (t & 3) * 8;
            int rk = key0 + key;
            int rkc = rk < nkeys ? rk : nkeys - 1;
            short8 kvv = *(const short8*)&K[((size_t)(b * nkeys + rkc)) * ldk + h * HDIM + kc];
            *(short8*)&K_s[key][kc] = kvv;
            short8 vvv = *(const short8*)&V[((size_t)(b * nkeys + rkc)) * ldv + h * HDIM + kc];
#pragma unroll
            for (int j = 0; j < 8; ++j) V_s[kc + j][key] = vvv[j];
        }
        __syncthreads();

        short8 aq = *(short8*)&Q_s[w * 16 + l15][lhi8];
        f32x4 sacc[4];
#pragma unroll
        for (int nf = 0; nf < 4; ++nf) {
#pragma unroll
            for (int r = 0; r < 4; ++r) sacc[nf][r] = 0.f;
            short8 kb = *(short8*)&K_s[nf * 16 + l15][lhi8];
            sacc[nf] = __builtin_amdgcn_mfma_f32_16x16x32_bf16(aq, kb, sacc[nf], 0, 0, 0);
        }

        const int ktg = key0 >> 6;
        const bool kv0 = key0 +      l15 < nkeys;
        const bool kv1 = key0 + 16 + l15 < nkeys;
        const bool kv2 = key0 + 32 + l15 < nkeys;
        const bool kv3 = key0 + 48 + l15 < nkeys;
        float c_r[4];
#pragma unroll
        for (int r = 0; r < 4; ++r) {
            float ryv = HAS_RPE ? ryp[r][ktg] : 0.f;
            float sv0 = sacc[0][r] + ryv, sv1 = sacc[1][r] + ryv;
            float sv2 = sacc[2][r] + ryv, sv3 = sacc[3][r] + ryv;
            if (HAS_RPE) {
                sv0 += rxv[r][0]; sv1 += rxv[r][1];
                sv2 += rxv[r][2]; sv3 += rxv[r][3];
            }
            sv0 = kv0 ? sv0 : -1e30f;
            sv1 = kv1 ? sv1 : -1e30f;
            sv2 = kv2 ? sv2 : -1e30f;
            sv3 = kv3 ? sv3 : -1e30f;
            float tmax = fmaxf(fmaxf(sv0, sv1), fmaxf(sv2, sv3));
#pragma unroll
            for (int mask = 1; mask < 16; mask <<= 1)
                tmax = fmaxf(tmax, __shfl_xor(tmax, mask));
            float mn = fmaxf(m_r[r], tmax);
            float cc = __expf(m_r[r] - mn);
            m_r[r] = mn; c_r[r] = cc;
            float p0 = __expf(sv0 - mn), p1 = __expf(sv1 - mn);
            float p2 = __expf(sv2 - mn), p3 = __expf(sv3 - mn);
            float ps = p0 + p1 + p2 + p3;
#pragma unroll
            for (int mask = 1; mask < 16; mask <<= 1) ps += __shfl_xor(ps, mask);
            l_r[r] = l_r[r] * cc + ps;
            P_s[w][lhi4 + r][     l15] = f2bf(p0);
            P_s[w][lhi4 + r][16 + l15] = f2bf(p1);
            P_s[w][lhi4 + r][32 + l15] = f2bf(p2);
            P_s[w][lhi4 + r][48 + l15] = f2bf(p3);
        }
#pragma unroll
        for (int ni = 0; ni < 2; ++ni)
#pragma unroll
            for (int r = 0; r < 4; ++r) oacc[ni][r] *= c_r[r];

        short8 pa0 = *(short8*)&P_s[w][l15][lhi8];
        short8 pa1 = *(short8*)&P_s[w][l15][32 + lhi8];
#pragma unroll
        for (int ni = 0; ni < 2; ++ni) {
            short8 vb0 = *(short8*)&V_s[ni * 16 + l15][lhi8];
            short8 vb1 = *(short8*)&V_s[ni * 16 + l15][32 + lhi8];
            oacc[ni] = __builtin_amdgcn_mfma_f32_16x16x32_bf16(pa0, vb0, oacc[ni], 0, 0, 0);
            oacc[ni] = __builtin_amdgcn_mfma_f32_16x16x32_bf16(pa1, vb1, oacc[ni], 0, 0, 0);
        }
    }

#pragma unroll
    for (int r = 0; r < 4; ++r) {
        int qi = q0 + w * 16 + lhi4 + r;
        if (qi < NQ) {
            size_t base = ((size_t)(bh * nsplit + sp) * NQ + qi);
            if (l15 == 0) { pm[base] = m_r[r]; pl[base] = l_r[r]; }
            po[base * 32 + l15] = (ushort_t)f2bf(oacc[0][r]);
            po[base * 32 + 16 + l15] = (ushort_t)f2bf(oacc[1][r]);
        }
    }
}

// ---------------------------------------------------------------------------
// Fused split-combine + output projection (N=K=256), bf16 W direct-load.
// ---------------------------------------------------------------------------
__global__ __launch_bounds__(256) void combine_gemm(
    const ushort_t* __restrict__ po, const float* __restrict__ pm,
    const float* __restrict__ pl, int nsplit,
    const ushort_t* __restrict__ W, const float* __restrict__ bias,
    float* __restrict__ C, int M)
{
    __shared__ short A_s2[64][264];
    const int t = threadIdx.x;
    const int m0 = blockIdx.y * 64, n0 = blockIdx.x * 64;

    // phase 1: combine -> A_s2 (bf16)
    {
        int rloc = t >> 2;
        int row = m0 + rloc;
        int dc = (t & 3) * 64;
        if (row < M) {
            int b = row / NQ, q = row % NQ;
#pragma unroll
            for (int hh = 0; hh < 2; ++hh) {
                int h = (dc >> 5) + hh;
                int bh = b * NHEAD + h;
                float Mx = -1e30f;
                for (int s = 0; s < nsplit; ++s)
                    Mx = fmaxf(Mx, pm[(size_t)(bh * nsplit + s) * NQ + q]);
                float L = 0.f;
                float acc[32];
#pragma unroll
                for (int d = 0; d < 32; ++d) acc[d] = 0.f;
                for (int s = 0; s < nsplit; ++s) {
                    size_t base = (size_t)(bh * nsplit + s) * NQ + q;
                    float wgt = __expf(pm[base] - Mx);
                    L += pl[base] * wgt;
                    const ushort_t* pp = &po[base * 32];
#pragma unroll
                    for (int d = 0; d < 32; ++d) acc[d] += bf2f(pp[d]) * wgt;
                }
                float inv = 1.f / L;
#pragma unroll
                for (int d = 0; d < 32; ++d)
                    A_s2[rloc][dc + hh * 32 + d] = f2bf(acc[d] * inv);
            }
        } else {
#pragma unroll
            for (int d = 0; d < 64; ++d) A_s2[rloc][dc + d] = 0;
        }
    }
    __syncthreads();

    const int lane = t & 63, w = t >> 6;
    const int wr = w >> 1, wc = w & 1;
    const int l15 = lane & 15, lhi8 = (lane >> 4) * 8;
    const ushort_t* wp0 = &W[(size_t)(n0 + wc * 32 + l15) * 256 + lhi8];
    const ushort_t* wp1 = wp0 + 16 * 256;
    f32x4 acc[2][2];
#pragma unroll
    for (int i = 0; i < 2; ++i)
#pragma unroll
        for (int j = 0; j < 2; ++j)
#pragma unroll
            for (int r = 0; r < 4; ++r) acc[i][j][r] = 0.f;

#pragma unroll
    for (int k0 = 0; k0 < 256; k0 += 32) {
        short8 a0 = *(short8*)&A_s2[wr * 32 + l15][k0 + lhi8];
        short8 a1 = *(short8*)&A_s2[wr * 32 + 16 + l15][k0 + lhi8];
        short8 b0 = *(const short8*)(wp0 + k0);
        short8 b1 = *(const short8*)(wp1 + k0);
        acc[0][0] = __builtin_amdgcn_mfma_f32_16x16x32_bf16(a0, b0, acc[0][0], 0, 0, 0);
        acc[0][1] = __builtin_amdgcn_mfma_f32_16x16x32_bf16(a0, b1, acc[0][1], 0, 0, 0);
        acc[1][0] = __builtin_amdgcn_mfma_f32_16x16x32_bf16(a1, b0, acc[1][0], 0, 0, 0);
        acc[1][1] = __builtin_amdgcn_mfma_f32_16x16x32_bf16(a1, b1, acc[1][1], 0, 0, 0);
    }

    const int rowb = m0 + wr * 32 + (lane >> 4) * 4;
    const int colb = n0 + wc * 32 + l15;
#pragma unroll
    for (int ni = 0; ni < 2; ++ni) {
        int col = colb + ni * 16;
        float bv = bias[col];
#pragma unroll
        for (int mi = 0; mi < 2; ++mi)
#pragma unroll
            for (int r = 0; r < 4; ++r) {
                int row = rowb + mi * 16 + r;
                if (row < M)
                    C[(size_t)row * 256 + col] = acc[mi][ni][r] + bv;
            }
    }
}

// ---------------------------------------------------------------------------
extern "C" void kernel_launch(void* const* d_in, const int* in_sizes, int n_in,
                              void* d_out, int out_size, void* d_ws, size_t ws_size,
                              hipStream_t stream)
{
    const float* tgt   = (const float*)d_in[0];
    const float* qpos  = (const float*)d_in[1];
    const float* refp  = (const float*)d_in[2];
    const float* src   = (const float*)d_in[3];
    const float* spe   = (const float*)d_in[4];
    const float* sa_in_w  = (const float*)d_in[6];
    const float* sa_in_b  = (const float*)d_in[7];
    const float* sa_out_w = (const float*)d_in[8];
    const float* sa_out_b = (const float*)d_in[9];
    const float* n1_w  = (const float*)d_in[10];
    const float* n1_b  = (const float*)d_in[11];
    const float* ca_q_w = (const float*)d_in[12];
    const float* ca_q_b = (const float*)d_in[13];
    const float* ca_k_w = (const float*)d_in[14];
    const float* ca_k_b = (const float*)d_in[15];
    const float* ca_v_w = (const float*)d_in[16];
    const float* ca_v_b = (const float*)d_in[17];
    const float* ca_p_w = (const float*)d_in[18];
    const float* ca_p_b = (const float*)d_in[19];
    const float* cpb1_w1 = (const float*)d_in[20];
    const float* cpb1_b1 = (const float*)d_in[21];
    const float* cpb1_w2 = (const float*)d_in[22];
    const float* cpb2_w1 = (const float*)d_in[23];
    const float* cpb2_b1 = (const float*)d_in[24];
    const float* cpb2_w2 = (const float*)d_in[25];
    const float* n2_w = (const float*)d_in[26];
    const float* n2_b = (const float*)d_in[27];
    const float* ffn_w1 = (const float*)d_in[28];
    const float* ffn_b1 = (const float*)d_in[29];
    const float* ffn_w2 = (const float*)d_in[30];
    const float* ffn_b2 = (const float*)d_in[31];
    const float* n3_w = (const float*)d_in[32];
    const float* n3_b = (const float*)d_in[33];

    float* ws  = (float*)d_ws;
    float* outb = ws;                        // 153600
    float* tb   = outb + 153600;             // 153600
    float* rx6  = tb + 153600;               // 6*307200
    float* ry6  = rx6 + 1843200;             // 6*307200
    float* boxx = ry6 + 1843200;             // 1200
    float* boxy = boxx + 1200;               // 1200
    float* pm   = boxy + 1200;               // 38400
    float* pl   = pm + 38400;                // 38400
    ushort_t* u = (ushort_t*)(pl + 38400);
    ushort_t* qkvb   = u;                    // 460800
    ushort_t* qcb    = qkvb + 460800;        // 153600
    ushort_t* ob16   = qcb + 153600;         // 153600
    ushort_t* oq16   = ob16 + 153600;        // 153600
    ushort_t* hbb    = oq16 + 153600;        // 614400
    ushort_t* poh    = hbb + 614400;         // 1228800
    ushort_t* kvb16  = poh + 1228800;        // 2097152
    ushort_t* srcb16 = kvb16 + 2097152;      // 2097152
    ushort_t* Kcb    = srcb16 + 2097152;     // 12582912
    ushort_t* Vcb    = Kcb + 12582912;       // 12582912
    ushort_t* Wseg   = Vcb + 12582912;       // 6291456
    ushort_t* Wsain  = Wseg;                 // 1179648
    ushort_t* Wsaout = Wsain + 1179648;      // 393216
    ushort_t* Wcaq   = Wsaout + 393216;
    ushort_t* Wcak   = Wcaq + 393216;
    ushort_t* Wcav   = Wcak + 393216;
    ushort_t* Wcap   = Wcav + 393216;
    ushort_t* Wff1   = Wcap + 393216;        // 1572864
    ushort_t* Wff2   = Wff1 + 1572864;       // 1572864

    const int M = BB * NQ;            // 600

    prep_kernel<<<8192, 256, 0, stream>>>(src, spe, tgt, qpos, refp,
        kvb16, srcb16, outb, ob16, oq16, boxx, boxy);
    wconv_kernel<<<3072, 256, 0, stream>>>(sa_in_w, sa_out_w, ca_q_w, ca_k_w,
        ca_v_w, ca_p_w, ffn_w1, ffn_w2, Wseg);
    rpe_all<<<dim3(150, 2, 6), 256, 0, stream>>>(boxx, boxy,
        cpb1_w1, cpb1_b1, cpb1_w2, cpb2_w1, cpb2_b1, cpb2_w2, rx6, ry6);
    kv_mega<<<dim3(4, 128, 2), 256, 0, stream>>>(kvb16, srcb16, Wcak, Wcav,
        ca_k_b, ca_v_b, Kcb, Vcb);

    for (int l = 0; l < NLAYER; ++l) {
        // ---- self attention ----
        gemm_direct<1,0><<<dim3(12, 10), 256, 0, stream>>>(
            oq16, ob16, 512, 256, Wsain + (size_t)l * 196608, sa_in_b + (size_t)l * 768,
            qkvb, 768, M, 256, ATTN_SCALE, 256);
        attn_mfma<0><<<dim3(5, 16, 5), 256, 0, stream>>>(
            qkvb, 768, qkvb + 256, 768, qkvb + 512, 768,
            NQ, 64, nullptr, nullptr, poh, pm, pl, 5);
        combine_gemm<<<dim3(4, 10), 256, 0, stream>>>(
            poh, pm, pl, 5, Wsaout + (size_t)l * 65536, sa_out_b + l * 256, tb, M);
        ln_residual<<<150, 256, 0, stream>>>(outb, tb, qpos,
            n1_w + l * 256, n1_b + l * 256, ob16, oq16, M);

        // ---- cross attention ----
        gemm_direct<1,0><<<dim3(4, 10), 256, 0, stream>>>(
            oq16, oq16, 256, 256, Wcaq + (size_t)l * 65536, ca_q_b + l * 256,
            qcb, 256, M, 256, ATTN_SCALE, 256);
        attn_mfma<1><<<dim3(5, 16, 8), 256, 0, stream>>>(
            qcb, 256, Kcb + (size_t)l * 2097152, 256, Vcb + (size_t)l * 2097152, 256,
            NKV, 512, rx6 + (size_t)l * 307200, ry6 + (size_t)l * 307200,
            poh, pm, pl, 8);
        combine_gemm<<<dim3(4, 10), 256, 0, stream>>>(
            poh, pm, pl, 8, Wcap + (size_t)l * 65536, ca_p_b + l * 256, tb, M);
        ln_residual<<<150, 256, 0, stream>>>(outb, tb, qpos,
            n2_w + l * 256, n2_b + l * 256, ob16, oq16, M);

        // ---- FFN ----
        gemm_direct<1,1><<<dim3(16, 10), 256, 0, stream>>>(
            ob16, ob16, 1024, 256, Wff1 + (size_t)l * 262144, ffn_b1 + l * 1024,
            hbb, 1024, M, 256, 1.f, 0);
        gemm_direct<0,0><<<dim3(4, 10), 256, 0, stream>>>(
            hbb, hbb, 256, 1024, Wff2 + (size_t)l * 262144, ffn_b2 + l * 256,
            tb, 256, M, 1024, 1.f, 0);
        ln_residual<<<150, 256, 0, stream>>>(outb, tb, qpos,
            n3_w + l * 256, n3_b + l * 256, ob16, oq16, M);
    }

    hipMemcpyAsync(d_out, outb, (size_t)M * DMODEL * sizeof(float),
                   hipMemcpyDeviceToDevice, stream);
}